// Round 4
// baseline (265.023 us; speedup 1.0000x reference)
//
#include <hip/hip_runtime.h>
#include <cstdint>

typedef unsigned short u16;
typedef unsigned int   u32;
typedef _Float16 f16;

typedef __attribute__((ext_vector_type(8))) _Float16 f16x8;   // 8 fp16 = 4 VGPRs
typedef __attribute__((ext_vector_type(4))) float    f32x4;   // MFMA accumulator

__device__ __forceinline__ u16 f2h(float f) {
    union { f16 h; u16 u; } c; c.h = (f16)f; return c.u;      // v_cvt_f16_f32 RTNE
}
__device__ __forceinline__ float h2f(u16 u) {
    union { u16 u; f16 h; } c; c.u = u; return (float)c.h;
}

// async global->LDS, 16B per lane; LDS dest = wave-uniform base + lane*16
__device__ __forceinline__ void async_copy16(const u16* g, u16* lds) {
    __builtin_amdgcn_global_load_lds(
        (const __attribute__((address_space(1))) void*)g,
        (__attribute__((address_space(3))) void*)lds,
        16, 0, 0);
}

// ---------------------------------------------------------------------------
// fp16 NT GEMM core, BK=64 as two 32-wide sub-tiles (proven r3 structure):
//   C[128,128] += A[128,K] * B[128,K]^T, K contiguous both.
// 256 thr = 4 waves (2x2), each wave 64x64 = 4x4 MFMA 16x16x32.
// LDS 32 KB: As0@0, As1@4096, Bs0@8192, Bs1@12288 (u16), each [128][32]
// XOR-swizzled (0 bank conflicts measured).  stage -> sync -> 2x compute -> sync.
// ---------------------------------------------------------------------------
__device__ __forceinline__ void gemm_nt_f16(
    u16* smem, const u16* __restrict__ A, int lda,
    const u16* __restrict__ B, int ldb, int K, f32x4 acc[4][4])
{
    const int t = threadIdx.x, w = t >> 6, lane = t & 63;
    const int srow = lane >> 2;                    // 0..15 within chunk
    const int skc  = (((lane & 3) ^ ((lane >> 3) & 3)) * 8);  // swizzled
    const int ra0 = (w*2+0)*16 + srow, ra1 = (w*2+1)*16 + srow;
    const u16* gA0 = A + (size_t)ra0 * lda + skc;
    const u16* gA1 = A + (size_t)ra1 * lda + skc;
    const u16* gB0 = B + (size_t)ra0 * ldb + skc;
    const u16* gB1 = B + (size_t)ra1 * ldb + skc;
    u16* lA0 = smem + (w*2+0)*512;                 // row base within a 32-wide tile
    u16* lA1 = smem + (w*2+1)*512;
    const int fr = lane & 15, fq = lane >> 4;
    const int fc = (fq ^ ((fr >> 1) & 3)) * 8;     // swizzled fragment chunk
    const int wm = (w >> 1) * 64, wn = (w & 1) * 64;
    const int fAo = (wm + fr) * 32 + fc;
    const int fBo = (wn + fr) * 32 + fc;

    for (int k0 = 0; k0 < K; k0 += 64) {
        async_copy16(gA0 + k0,      lA0);
        async_copy16(gA1 + k0,      lA1);
        async_copy16(gA0 + k0 + 32, lA0 + 4096);
        async_copy16(gA1 + k0 + 32, lA1 + 4096);
        async_copy16(gB0 + k0,      lA0 + 8192);
        async_copy16(gB1 + k0,      lA1 + 8192);
        async_copy16(gB0 + k0 + 32, lA0 + 12288);
        async_copy16(gB1 + k0 + 32, lA1 + 12288);
        __syncthreads();
        {   // k-sub 0
            f16x8 af[4], bf[4];
#pragma unroll
            for (int i = 0; i < 4; i++) af[i] = *(const f16x8*)(smem + fAo + i * 512);
#pragma unroll
            for (int i = 0; i < 4; i++) bf[i] = *(const f16x8*)(smem + 8192 + fBo + i * 512);
#pragma unroll
            for (int mi = 0; mi < 4; mi++)
#pragma unroll
                for (int ni = 0; ni < 4; ni++)
                    acc[mi][ni] = __builtin_amdgcn_mfma_f32_16x16x32_f16(
                        af[mi], bf[ni], acc[mi][ni], 0, 0, 0);
        }
        {   // k-sub 1
            f16x8 af[4], bf[4];
#pragma unroll
            for (int i = 0; i < 4; i++) af[i] = *(const f16x8*)(smem + 4096 + fAo + i * 512);
#pragma unroll
            for (int i = 0; i < 4; i++) bf[i] = *(const f16x8*)(smem + 12288 + fBo + i * 512);
#pragma unroll
            for (int mi = 0; mi < 4; mi++)
#pragma unroll
                for (int ni = 0; ni < 4; ni++)
                    acc[mi][ni] = __builtin_amdgcn_mfma_f32_16x16x32_f16(
                        af[mi], bf[ni], acc[mi][ni], 0, 0, 0);
        }
        __syncthreads();
    }
}

__device__ __forceinline__ void zero_acc(f32x4 acc[4][4]) {
#pragma unroll
    for (int i = 0; i < 4; i++)
#pragma unroll
        for (int j = 0; j < 4; j++) {
            f32x4 z = {0.f, 0.f, 0.f, 0.f};
            acc[i][j] = z;
        }
}

// ---------------------------------------------------------------------------
// k_prep: blocks 0..511  : Wq -> duplicated f16 [512][1024] ([Wq|Wq]),
//                          Wk -> f16 [512][512]; zero rowsum accumulator s.
//         blocks 512..575: WvT[c][d] = f16(wv[d][c])
// ---------------------------------------------------------------------------
__global__ __launch_bounds__(256) void k_prep(const float* __restrict__ wq,
                                              const float* __restrict__ wk,
                                              const float* __restrict__ wv,
                                              u16* __restrict__ Wq2,
                                              u16* __restrict__ Wkh,
                                              u16* __restrict__ WvT,
                                              float* __restrict__ s)
{
    if (blockIdx.x < 512) {
        const int t = blockIdx.x * 256 + threadIdx.x;   // 0..131071
        if (t < 4096) s[t] = 0.f;
        const int e = t * 4;
        const int sel = e >> 18;                        // 0: wq, 1: wk
        const int off = e & 262143;
        const float* src = sel ? wk : wq;
        float4 v = *(const float4*)(src + off);
        ushort4 h;
        h.x = f2h(v.x); h.y = f2h(v.y); h.z = f2h(v.z); h.w = f2h(v.w);
        if (sel == 0) {
            int i = off >> 9, c = off & 511;
            *(ushort4*)(Wq2 + (size_t)i * 1024 + c) = h;
            *(ushort4*)(Wq2 + (size_t)i * 1024 + 512 + c) = h;
        } else {
            *(ushort4*)(Wkh + off) = h;
        }
    } else {
        __shared__ u16 tile[64][70];
        const int bx = blockIdx.x - 512;                // 0..63
        const int t = threadIdx.x;
        const int d0 = (bx >> 3) * 64;
        const int c0 = (bx & 7) * 64;
        const int rr = t >> 4, col4 = (t & 15) * 4;
#pragma unroll
        for (int i = 0; i < 4; i++) {
            int row = i * 16 + rr;                      // d offset
            float4 v = *(const float4*)(wv + (size_t)(d0 + row) * 512 + c0 + col4);
            ushort4 h;
            h.x = f2h(v.x); h.y = f2h(v.y); h.z = f2h(v.z); h.w = f2h(v.w);
            *(ushort4*)&tile[row][col4] = h;
        }
        __syncthreads();
#pragma unroll
        for (int i = 0; i < 4; i++) {
            int crow = i * 16 + rr;                     // c offset
            ushort4 o;
            o.x = tile[col4 + 0][crow];
            o.y = tile[col4 + 1][crow];
            o.z = tile[col4 + 2][crow];
            o.w = tile[col4 + 3][crow];
            *(ushort4*)(WvT + (size_t)(c0 + crow) * 512 + d0 + col4) = o;
        }
    }
}

// ---------------------------------------------------------------------------
// k_convx: x f32 [B,512,4096] -> Xh f16 (same layout) + XT f16 [B,4096,512]
//          + rowsums s[b][c] = sum_n x  (f32 atomics, s pre-zeroed by k_prep)
// ---------------------------------------------------------------------------
__global__ __launch_bounds__(256) void k_convx(const float* __restrict__ x,
                                               u16* __restrict__ Xh,
                                               u16* __restrict__ XT,
                                               float* __restrict__ s)
{
    __shared__ u16 tile[64][70];
    const int t  = threadIdx.x;
    const int b  = blockIdx.z;
    const int c0 = blockIdx.y * 64;
    const int n0 = blockIdx.x * 64;
    const int rr   = t >> 4;
    const int col4 = (t & 15) * 4;

    const float* src = x + ((size_t)b * 512 + c0) * 4096 + n0;
    u16* xh = Xh + ((size_t)b * 512 + c0) * 4096 + n0;
#pragma unroll
    for (int i = 0; i < 4; i++) {
        int row = i * 16 + rr;
        float4 v = *(const float4*)(src + (size_t)row * 4096 + col4);
        ushort4 h;
        h.x = f2h(v.x); h.y = f2h(v.y); h.z = f2h(v.z); h.w = f2h(v.w);
        *(ushort4*)&tile[row][col4] = h;
        *(ushort4*)(xh + (size_t)row * 4096 + col4) = h;
        float p = v.x + v.y + v.z + v.w;
        p += __shfl_xor(p, 1); p += __shfl_xor(p, 2);
        p += __shfl_xor(p, 4); p += __shfl_xor(p, 8);
        if ((t & 15) == 0) atomicAdd(&s[b * 512 + c0 + row], p);
    }
    __syncthreads();
    u16* dst = XT + ((size_t)b * 4096 + n0) * 512 + c0;
#pragma unroll
    for (int i = 0; i < 4; i++) {
        int nrow = i * 16 + rr;
        ushort4 o;
        o.x = tile[col4 + 0][nrow];
        o.y = tile[col4 + 1][nrow];
        o.z = tile[col4 + 2][nrow];
        o.w = tile[col4 + 3][nrow];
        *(ushort4*)(dst + (size_t)nrow * 512 + col4) = o;
    }
}

// ---------------------------------------------------------------------------
// k_gram: symmetric Gram.  Only the 10 upper-triangle 128^2 tiles are
// computed (tile index bx 0..9 -> (tm<=tn)); off-diagonal tiles also write
// the mirrored tile (float4 along m, since acc r-index = 4 consecutive m).
// Gp[ks][b] = Xh[b, :, ks*1024:+1024] * (same)^T   split-K=4, f32 out.
// grid (10, 32): by = b*4 + ks.   320 blocks.
// ---------------------------------------------------------------------------
__global__ __launch_bounds__(256, 4) void k_gram(const u16* __restrict__ Xh,
                                                 float* __restrict__ Gp)
{
    __shared__ u16 smem[16384];          // 32 KB
    const int tI = blockIdx.x;           // 0..9
    const int tm = (tI >= 9) ? 3 : (tI >= 7) ? 2 : (tI >= 4) ? 1 : 0;
    const int rs = (tm == 0) ? 0 : (tm == 1) ? 4 : (tm == 2) ? 7 : 9;
    const int tn = tI - rs + tm;
    const int m0 = tm * 128, n0 = tn * 128;
    const int bz = blockIdx.y;
    const int b  = bz >> 2, ks = bz & 3;

    const u16* Ap = Xh + (size_t)b * 512 * 4096 + (size_t)m0 * 4096 + ks * 1024;
    const u16* Bp = Xh + (size_t)b * 512 * 4096 + (size_t)n0 * 4096 + ks * 1024;

    f32x4 acc[4][4];
    zero_acc(acc);
    gemm_nt_f16(smem, Ap, 4096, Bp, 4096, 1024, acc);

    const int t = threadIdx.x, w = t >> 6, lane = t & 63;
    const int wm = (w >> 1) * 64, wn = (w & 1) * 64;
    const int cn = lane & 15, cq = lane >> 4;

    float* base = Gp + (size_t)(ks * 8 + b) * 512 * 512;
    float* outp = base + (size_t)m0 * 512 + n0;
#pragma unroll
    for (int mi = 0; mi < 4; mi++)
#pragma unroll
        for (int ni = 0; ni < 4; ni++)
#pragma unroll
            for (int r = 0; r < 4; r++) {
                int m = wm + mi * 16 + cq * 4 + r;
                int n = wn + ni * 16 + cn;
                outp[(size_t)m * 512 + n] = acc[mi][ni][r];
            }
    if (m0 != n0) {                      // mirror: G[n][m] = G[m][n]
        float* outT = base + (size_t)n0 * 512 + m0;
#pragma unroll
        for (int mi = 0; mi < 4; mi++)
#pragma unroll
            for (int ni = 0; ni < 4; ni++) {
                int mb = wm + mi * 16 + cq * 4;        // 4 consecutive m
                int n  = wn + ni * 16 + cn;
                float4 v4 = { acc[mi][ni][0], acc[mi][ni][1],
                              acc[mi][ni][2], acc[mi][ni][3] };
                *(float4*)(outT + (size_t)n * 512 + mb) = v4;
            }
    }
}

// ---------------------------------------------------------------------------
// k_gred: G = sum of 4 split-K partials; store hi/lo f16 pair
// Ghl[b][d][0:512] = hi(G[d][:]), [512:1024] = lo.
// blocks 0..127 additionally compute (fused k_uv):
//   ubar[b][i] = (Wq s_b)[i] + 4096*bq[i];  vv[b][j] = (Wk s_b)[j]
// ---------------------------------------------------------------------------
__global__ __launch_bounds__(256) void k_gred(const float* __restrict__ Gp,
                                              u16* __restrict__ Ghl,
                                              const float* __restrict__ wq,
                                              const float* __restrict__ bq,
                                              const float* __restrict__ wk,
                                              const float* __restrict__ s,
                                              float* __restrict__ ubar,
                                              float* __restrict__ vv)
{
    const size_t idx = ((size_t)blockIdx.x * 256 + threadIdx.x) * 4;
    const size_t st = (size_t)8 * 512 * 512;
    float4 g0 = *(const float4*)(Gp + idx);
    float4 g1 = *(const float4*)(Gp + idx + st);
    float4 g2 = *(const float4*)(Gp + idx + 2 * st);
    float4 g3 = *(const float4*)(Gp + idx + 3 * st);
    float gx = g0.x + g1.x + g2.x + g3.x;
    float gy = g0.y + g1.y + g2.y + g3.y;
    float gz = g0.z + g1.z + g2.z + g3.z;
    float gw = g0.w + g1.w + g2.w + g3.w;
    ushort4 hi, lo;
    hi.x = f2h(gx); lo.x = f2h(gx - h2f(hi.x));
    hi.y = f2h(gy); lo.y = f2h(gy - h2f(hi.y));
    hi.z = f2h(gz); lo.z = f2h(gz - h2f(hi.z));
    hi.w = f2h(gw); lo.w = f2h(gw - h2f(hi.w));
    const size_t row = idx >> 9;                 // b*512 + d
    const int c = (int)(idx & 511);
    *(ushort4*)(Ghl + row * 1024 + c) = hi;
    *(ushort4*)(Ghl + row * 1024 + 512 + c) = lo;

    if (blockIdx.x < 128) {                      // fused k_uv
        const int b = blockIdx.x >> 4;
        const int sub = blockIdx.x & 15;
        const int which = sub >> 3;
        const int r0 = (sub & 7) * 64;
        const int t = threadIdx.x;
        const int i = r0 + (t >> 2), l4 = t & 3;
        const float* W = which ? wk : wq;
        const float* sb = s + b * 512;
        float acc = 0.f;
#pragma unroll 4
        for (int k = 0; k < 32; k++) {
            int c2 = k * 16 + l4 * 4;
            float4 w4 = *(const float4*)(W + (size_t)i * 512 + c2);
            float4 s4 = *(const float4*)(sb + c2);
            acc += w4.x * s4.x + w4.y * s4.y + w4.z * s4.z + w4.w * s4.w;
        }
        acc += __shfl_xor(acc, 1);
        acc += __shfl_xor(acc, 2);
        if (l4 == 0) {
            if (which) vv[b * 512 + i] = acc;
            else       ubar[b * 512 + i] = acc + 4096.0f * bq[i];
        }
    }
}

// ---------------------------------------------------------------------------
// k_TSM: fused T -> S/softmax -> M for 16 S-rows per block.  grid (32, 8).
//  phase T: T[16,512] = Wq2[m0:16, 0:1024] * Ghl_b[512, 1024]^T  (hi/lo K)
//           -> f16 -> Ts (LDS, A-frag swizzled layout)
//  phase S: S[16,512] = Ts * Wkh^T + ubar*bk^T + bq*vv^T -> row softmax
//           -> P f16 -> Ps (LDS, reuses Ts region); also pbv row dots
//  phase M: M2[16,512] = Ps * WvT^T  -> global f16
// 4 waves; wave w owns output cols [w*128, w*128+128) in every phase.
// LDS: Bs[512][32] (32KB) + As_w[16][32] (1KB) + Ts/Ps[16][512] (16KB) ~ 50KB.
// ---------------------------------------------------------------------------
__global__ __launch_bounds__(256) void k_TSM(
    const u16* __restrict__ Wq2, const u16* __restrict__ Ghl,
    const u16* __restrict__ Wkh, const u16* __restrict__ WvT,
    const float* __restrict__ ubar, const float* __restrict__ vv,
    const float* __restrict__ bq, const float* __restrict__ bk,
    const float* __restrict__ bv,
    u16* __restrict__ M2, float* __restrict__ pbv)
{
    __shared__ u16 smem[25088];          // Bs@0 (16384), As_w@16384 (512), Ts/Ps@16896 (8192)
    __shared__ float redm[16][4];
    __shared__ float reds[16][4][2];
    u16* Bs = smem;
    u16* As = smem + 16384;
    u16* Ts = smem + 16896;              // also Ps

    const int m0 = blockIdx.x * 16;
    const int b  = blockIdx.y;
    const int t = threadIdx.x, w = t >> 6, lane = t & 63;
    const int srow = lane >> 2;
    const int schunk = ((lane & 3) ^ ((srow >> 1) & 3)) * 8;
    const int fr = lane & 15, fq = lane >> 4;
    const int fc = (fq ^ ((fr >> 1) & 3)) * 8;
    const int cn = lane & 15, cq = lane >> 4;

    const u16* Ghl_b = Ghl + (size_t)b * 512 * 1024;

    f32x4 acc[8];

    // ---------------- phase T: K=1024 (hi/lo), B = Ghl_b (lda 1024) --------
#pragma unroll
    for (int i = 0; i < 8; i++) { f32x4 z = {0.f,0.f,0.f,0.f}; acc[i] = z; }
    {
        const u16* gA = Wq2 + (size_t)(m0 + srow) * 1024 + schunk;
        for (int k0 = 0; k0 < 1024; k0 += 32) {
            if (w == 0) async_copy16(gA + k0, As);
#pragma unroll
            for (int ii = 0; ii < 8; ii++) {
                int rbase = w * 128 + ii * 16;
                async_copy16(Ghl_b + (size_t)(rbase + srow) * 1024 + k0 + schunk,
                             Bs + rbase * 32);
            }
            __syncthreads();
            f16x8 af = *(const f16x8*)(As + fr * 32 + fc);
#pragma unroll
            for (int ni = 0; ni < 8; ni++) {
                f16x8 bf = *(const f16x8*)(Bs + (w * 128 + ni * 16 + fr) * 32 + fc);
                acc[ni] = __builtin_amdgcn_mfma_f32_16x16x32_f16(af, bf, acc[ni], 0, 0, 0);
            }
            __syncthreads();
        }
    }
    // store T (f16) into Ts with the A-frag swizzled layout:
    // element (row mr, col d) at [ (d>>5)*512 + mr*32 + ((lc ^ ((mr>>1)&3))<<3) + (d&7) ]
#pragma unroll
    for (int ni = 0; ni < 8; ni++) {
        const int d = w * 128 + ni * 16 + cn;
        const int kc = d >> 5, lc = (d & 31) >> 3, dl = d & 7;
#pragma unroll
        for (int r = 0; r < 4; r++) {
            int mr = cq * 4 + r;
            Ts[kc * 512 + mr * 32 + ((lc ^ ((mr >> 1) & 3)) << 3) + dl]
                = f2h(acc[ni][r]);
        }
    }

    // ---------------- phase S: K=512, A = Ts (LDS), B = Wkh ----------------
#pragma unroll
    for (int i = 0; i < 8; i++) { f32x4 z = {0.f,0.f,0.f,0.f}; acc[i] = z; }
    for (int k0 = 0; k0 < 512; k0 += 32) {
#pragma unroll
        for (int ii = 0; ii < 8; ii++) {
            int rbase = w * 128 + ii * 16;
            async_copy16(Wkh + (size_t)(rbase + srow) * 512 + k0 + schunk,
                         Bs + rbase * 32);
        }
        __syncthreads();                 // also makes Ts stores visible (1st iter)
        f16x8 af = *(const f16x8*)(Ts + (k0 >> 5) * 512 + fr * 32 + fc);
#pragma unroll
        for (int ni = 0; ni < 8; ni++) {
            f16x8 bf = *(const f16x8*)(Bs + (w * 128 + ni * 16 + fr) * 32 + fc);
            acc[ni] = __builtin_amdgcn_mfma_f32_16x16x32_f16(af, bf, acc[ni], 0, 0, 0);
        }
        __syncthreads();
    }

    // rank-1 bias terms + row softmax (rows complete within block)
    float ub[4], bqr[4];
#pragma unroll
    for (int r = 0; r < 4; r++) {
        int i = m0 + cq * 4 + r;
        ub[r]  = ubar[b * 512 + i];
        bqr[r] = bq[i];
    }
    float vj[8], bkj[8], bvj[8];
#pragma unroll
    for (int ni = 0; ni < 8; ni++) {
        int j = w * 128 + ni * 16 + cn;
        vj[ni]  = vv[b * 512 + j];
        bkj[ni] = bk[j];
        bvj[ni] = bv[j];
    }
    float sv[8][4], mr4[4];
#pragma unroll
    for (int r = 0; r < 4; r++) mr4[r] = -1e30f;
#pragma unroll
    for (int ni = 0; ni < 8; ni++)
#pragma unroll
        for (int r = 0; r < 4; r++) {
            sv[ni][r] = acc[ni][r] + ub[r] * bkj[ni] + bqr[r] * vj[ni];
            mr4[r] = fmaxf(mr4[r], sv[ni][r]);
        }
#pragma unroll
    for (int r = 0; r < 4; r++)
        for (int o = 1; o < 16; o <<= 1) mr4[r] = fmaxf(mr4[r], __shfl_xor(mr4[r], o));
    if (cn == 0) {
#pragma unroll
        for (int r = 0; r < 4; r++) redm[cq * 4 + r][w] = mr4[r];
    }
    __syncthreads();
#pragma unroll
    for (int r = 0; r < 4; r++) {
        int row = cq * 4 + r;
        mr4[r] = fmaxf(fmaxf(redm[row][0], redm[row][1]),
                       fmaxf(redm[row][2], redm[row][3]));
    }
    float e[8][4], se[4], sebv[4];
#pragma unroll
    for (int r = 0; r < 4; r++) { se[r] = 0.f; sebv[r] = 0.f; }
#pragma unroll
    for (int ni = 0; ni < 8; ni++)
#pragma unroll
        for (int r = 0; r < 4; r++) {
            float ev = __expf(sv[ni][r] - mr4[r]);
            e[ni][r] = ev;
            se[r]   += ev;
            sebv[r] += ev * bvj[ni];
        }
#pragma unroll
    for (int r = 0; r < 4; r++)
        for (int o = 1; o < 16; o <<= 1) {
            se[r]   += __shfl_xor(se[r], o);
            sebv[r] += __shfl_xor(sebv[r], o);
        }
    if (cn == 0) {
#pragma unroll
        for (int r = 0; r < 4; r++) {
            reds[cq * 4 + r][w][0] = se[r];
            reds[cq * 4 + r][w][1] = sebv[r];
        }
    }
    __syncthreads();
    float inv4[4];
#pragma unroll
    for (int r = 0; r < 4; r++) {
        int row = cq * 4 + r;
        float S  = reds[row][0][0] + reds[row][1][0] + reds[row][2][0] + reds[row][3][0];
        float SB = reds[row][0][1] + reds[row][1][1] + reds[row][2][1] + reds[row][3][1];
        inv4[r] = 1.0f / S;
        if (w == 0 && cn == 0) pbv[b * 512 + m0 + row] = SB * inv4[r];
    }
    // store P (f16) into Ps (reuses Ts region; Ts is dead) — same layout
#pragma unroll
    for (int ni = 0; ni < 8; ni++) {
        const int j = w * 128 + ni * 16 + cn;
        const int kc = j >> 5, lc = (j & 31) >> 3, jl = j & 7;
#pragma unroll
        for (int r = 0; r < 4; r++) {
            int mr = cq * 4 + r;
            Ts[kc * 512 + mr * 32 + ((lc ^ ((mr >> 1) & 3)) << 3) + jl]
                = f2h(e[ni][r] * inv4[r]);
        }
    }

    // ---------------- phase M: K=512, A = Ps (LDS), B = WvT ----------------
#pragma unroll
    for (int i = 0; i < 8; i++) { f32x4 z = {0.f,0.f,0.f,0.f}; acc[i] = z; }
    for (int k0 = 0; k0 < 512; k0 += 32) {
#pragma unroll
        for (int ii = 0; ii < 8; ii++) {
            int rbase = w * 128 + ii * 16;
            async_copy16(WvT + (size_t)(rbase + srow) * 512 + k0 + schunk,
                         Bs + rbase * 32);
        }
        __syncthreads();                 // also makes Ps stores visible (1st iter)
        f16x8 af = *(const f16x8*)(Ts + (k0 >> 5) * 512 + fr * 32 + fc);
#pragma unroll
        for (int ni = 0; ni < 8; ni++) {
            f16x8 bf = *(const f16x8*)(Bs + (w * 128 + ni * 16 + fr) * 32 + fc);
            acc[ni] = __builtin_amdgcn_mfma_f32_16x16x32_f16(af, bf, acc[ni], 0, 0, 0);
        }
        __syncthreads();
    }
#pragma unroll
    for (int ni = 0; ni < 8; ni++)
#pragma unroll
        for (int r = 0; r < 4; r++) {
            int mr = cq * 4 + r;
            M2[((size_t)b * 512 + m0 + mr) * 512 + w * 128 + ni * 16 + cn]
                = f2h(acc[ni][r]);
        }
}

// ---------------------------------------------------------------------------
// k_out: out = M2 * X + pbv*1^T + x_res   (residual from Xh f16), f32 out
// grid (32, 4, 8)
// ---------------------------------------------------------------------------
__global__ __launch_bounds__(256, 4) void k_out(const u16* __restrict__ M2,
                                                const u16* __restrict__ XT,
                                                const u16* __restrict__ Xh,
                                                const float* __restrict__ pbv,
                                                float* __restrict__ out)
{
    __shared__ u16 smem[16384];
    const int n0 = blockIdx.x * 128;
    const int m0 = blockIdx.y * 128;
    const int b  = blockIdx.z;

    const u16* Ap = M2 + (size_t)b * 512 * 512 + (size_t)m0 * 512;
    const u16* Bp = XT + (size_t)b * 4096 * 512 + (size_t)n0 * 512;

    f32x4 acc[4][4];
    zero_acc(acc);
    gemm_nt_f16(smem, Ap, 512, Bp, 512, 512, acc);

    const int t = threadIdx.x, w = t >> 6, lane = t & 63;
    const int wm = (w >> 1) * 64, wn = (w & 1) * 64;
    const int cn = lane & 15, cq = lane >> 4;

#pragma unroll
    for (int mi = 0; mi < 4; mi++)
#pragma unroll
        for (int ni = 0; ni < 4; ni++)
#pragma unroll
            for (int r = 0; r < 4; r++) {
                int m = m0 + wm + mi * 16 + cq * 4 + r;
                int n = n0 + wn + ni * 16 + cn;
                size_t idx = ((size_t)b * 512 + m) * 4096 + n;
                out[idx] = acc[mi][ni][r] + pbv[b * 512 + m] + h2f(Xh[idx]);
            }
}

// ---------------------------------------------------------------------------
// ws layout (bytes), high-water ~111 MiB:
//   Wq2  [512][1024] f16   @ 0          (1048576)
//   Wkh  [512][512]  f16   @ 1048576    (524288)
//   WvT  [512][512]  f16   @ 1572864    (524288)
//   s    [8][512]    f32   @ 2097152    (16384)
//   ubar [8][512]    f32   @ 2113536    (16384)
//   vv   [8][512]    f32   @ 2129920    (16384)
//   pbv  [8][512]    f32   @ 2146304    (16384)
//   Xh   [8][512][4096] f16 @ 2162688   (33554432)
//   XT   [8][4096][512] f16 @ 35717120  (33554432)
//   Gp   [4][8][512][512] f32 @ 69271552 (33554432)
//   Ghl  [8][512][1024] f16 @ 102825984 (8388608)
//   M2   [8][512][512] f16  @ 111214592 (4194304)
// ---------------------------------------------------------------------------
extern "C" void kernel_launch(void* const* d_in, const int* in_sizes, int n_in,
                              void* d_out, int out_size, void* d_ws, size_t ws_size,
                              hipStream_t stream)
{
    const float* x  = (const float*)d_in[0];
    const float* wq = (const float*)d_in[1];
    const float* bq = (const float*)d_in[2];
    const float* wk = (const float*)d_in[3];
    const float* bk = (const float*)d_in[4];
    const float* wv = (const float*)d_in[5];
    const float* bv = (const float*)d_in[6];
    float* out = (float*)d_out;

    char* ws = (char*)d_ws;
    u16*   Wq2  = (u16*)(ws);
    u16*   Wkh  = (u16*)(ws + 1048576);
    u16*   WvT  = (u16*)(ws + 1572864);
    float* s    = (float*)(ws + 2097152);
    float* ubar = (float*)(ws + 2113536);
    float* vv   = (float*)(ws + 2129920);
    float* pbv  = (float*)(ws + 2146304);
    u16*   Xh   = (u16*)(ws + 2162688);
    u16*   XT   = (u16*)(ws + 35717120);
    float* Gp   = (float*)(ws + 69271552);
    u16*   Ghl  = (u16*)(ws + 102825984);
    u16*   M2   = (u16*)(ws + 111214592);

    k_prep<<<dim3(576), dim3(256), 0, stream>>>(wq, wk, wv, Wq2, Wkh, WvT, s);
    k_convx<<<dim3(64, 8, 8), dim3(256), 0, stream>>>(x, Xh, XT, s);
    k_gram<<<dim3(10, 32), dim3(256), 0, stream>>>(Xh, Gp);
    k_gred<<<dim3(2048), dim3(256), 0, stream>>>(Gp, Ghl, wq, bq, wk, s, ubar, vv);
    k_TSM<<<dim3(32, 8), dim3(256), 0, stream>>>(Wq2, Ghl, Wkh, WvT, ubar, vv,
                                                 bq, bk, bv, M2, pbv);
    k_out<<<dim3(32, 4, 8), dim3(256), 0, stream>>>(M2, XT, Xh, pbv, out);
}

// Round 5
// 250.012 us; speedup vs baseline: 1.0600x; 1.0600x over previous
//
#include <hip/hip_runtime.h>
#include <cstdint>

typedef unsigned short u16;
typedef unsigned int   u32;
typedef _Float16 f16;

typedef __attribute__((ext_vector_type(8))) _Float16 f16x8;   // 8 fp16 = 4 VGPRs
typedef __attribute__((ext_vector_type(4))) float    f32x4;   // MFMA accumulator

__device__ __forceinline__ u16 f2h(float f) {
    union { f16 h; u16 u; } c; c.h = (f16)f; return c.u;      // v_cvt_f16_f32 RTNE
}
__device__ __forceinline__ float h2f(u16 u) {
    union { u16 u; f16 h; } c; c.u = u; return (float)c.h;
}

// async global->LDS, 16B per lane; LDS dest = wave-uniform base + lane*16
__device__ __forceinline__ void async_copy16(const u16* g, u16* lds) {
    __builtin_amdgcn_global_load_lds(
        (const __attribute__((address_space(1))) void*)g,
        (__attribute__((address_space(3))) void*)lds,
        16, 0, 0);
}

// ---------------------------------------------------------------------------
// fp16 NT GEMM core, BK=64 as two 32-wide sub-tiles (proven r3 structure):
//   C[128,128] += A[128,K] * B[128,K]^T, K contiguous both.
// 256 thr = 4 waves (2x2), each wave 64x64 = 4x4 MFMA 16x16x32.
// LDS 32 KB: As0@0, As1@4096, Bs0@8192, Bs1@12288 (u16), each [128][32]
// XOR-swizzled (0 bank conflicts measured).  stage -> sync -> 2x compute -> sync.
// ---------------------------------------------------------------------------
__device__ __forceinline__ void gemm_nt_f16(
    u16* smem, const u16* __restrict__ A, int lda,
    const u16* __restrict__ B, int ldb, int K, f32x4 acc[4][4])
{
    const int t = threadIdx.x, w = t >> 6, lane = t & 63;
    const int srow = lane >> 2;                    // 0..15 within chunk
    const int skc  = (((lane & 3) ^ ((lane >> 3) & 3)) * 8);  // swizzled
    const int ra0 = (w*2+0)*16 + srow, ra1 = (w*2+1)*16 + srow;
    const u16* gA0 = A + (size_t)ra0 * lda + skc;
    const u16* gA1 = A + (size_t)ra1 * lda + skc;
    const u16* gB0 = B + (size_t)ra0 * ldb + skc;
    const u16* gB1 = B + (size_t)ra1 * ldb + skc;
    u16* lA0 = smem + (w*2+0)*512;                 // row base within a 32-wide tile
    u16* lA1 = smem + (w*2+1)*512;
    const int fr = lane & 15, fq = lane >> 4;
    const int fc = (fq ^ ((fr >> 1) & 3)) * 8;     // swizzled fragment chunk
    const int wm = (w >> 1) * 64, wn = (w & 1) * 64;
    const int fAo = (wm + fr) * 32 + fc;
    const int fBo = (wn + fr) * 32 + fc;

    for (int k0 = 0; k0 < K; k0 += 64) {
        async_copy16(gA0 + k0,      lA0);
        async_copy16(gA1 + k0,      lA1);
        async_copy16(gA0 + k0 + 32, lA0 + 4096);
        async_copy16(gA1 + k0 + 32, lA1 + 4096);
        async_copy16(gB0 + k0,      lA0 + 8192);
        async_copy16(gB1 + k0,      lA1 + 8192);
        async_copy16(gB0 + k0 + 32, lA0 + 12288);
        async_copy16(gB1 + k0 + 32, lA1 + 12288);
        __syncthreads();
        {   // k-sub 0
            f16x8 af[4], bf[4];
#pragma unroll
            for (int i = 0; i < 4; i++) af[i] = *(const f16x8*)(smem + fAo + i * 512);
#pragma unroll
            for (int i = 0; i < 4; i++) bf[i] = *(const f16x8*)(smem + 8192 + fBo + i * 512);
#pragma unroll
            for (int mi = 0; mi < 4; mi++)
#pragma unroll
                for (int ni = 0; ni < 4; ni++)
                    acc[mi][ni] = __builtin_amdgcn_mfma_f32_16x16x32_f16(
                        af[mi], bf[ni], acc[mi][ni], 0, 0, 0);
        }
        {   // k-sub 1
            f16x8 af[4], bf[4];
#pragma unroll
            for (int i = 0; i < 4; i++) af[i] = *(const f16x8*)(smem + 4096 + fAo + i * 512);
#pragma unroll
            for (int i = 0; i < 4; i++) bf[i] = *(const f16x8*)(smem + 12288 + fBo + i * 512);
#pragma unroll
            for (int mi = 0; mi < 4; mi++)
#pragma unroll
                for (int ni = 0; ni < 4; ni++)
                    acc[mi][ni] = __builtin_amdgcn_mfma_f32_16x16x32_f16(
                        af[mi], bf[ni], acc[mi][ni], 0, 0, 0);
        }
        __syncthreads();
    }
}

__device__ __forceinline__ void zero_acc(f32x4 acc[4][4]) {
#pragma unroll
    for (int i = 0; i < 4; i++)
#pragma unroll
        for (int j = 0; j < 4; j++) {
            f32x4 z = {0.f, 0.f, 0.f, 0.f};
            acc[i][j] = z;
        }
}

// ---------------------------------------------------------------------------
// k_prep: blocks 0..511  : Wq -> duplicated f16 [512][1024] ([Wq|Wq]),
//                          Wk -> f16 [512][512]; zero rowsum accumulator s.
//         blocks 512..575: WvT[c][d] = f16(wv[d][c])
// ---------------------------------------------------------------------------
__global__ __launch_bounds__(256) void k_prep(const float* __restrict__ wq,
                                              const float* __restrict__ wk,
                                              const float* __restrict__ wv,
                                              u16* __restrict__ Wq2,
                                              u16* __restrict__ Wkh,
                                              u16* __restrict__ WvT,
                                              float* __restrict__ s)
{
    if (blockIdx.x < 512) {
        const int t = blockIdx.x * 256 + threadIdx.x;   // 0..131071
        if (t < 4096) s[t] = 0.f;
        const int e = t * 4;
        const int sel = e >> 18;                        // 0: wq, 1: wk
        const int off = e & 262143;
        const float* src = sel ? wk : wq;
        float4 v = *(const float4*)(src + off);
        ushort4 h;
        h.x = f2h(v.x); h.y = f2h(v.y); h.z = f2h(v.z); h.w = f2h(v.w);
        if (sel == 0) {
            int i = off >> 9, c = off & 511;
            *(ushort4*)(Wq2 + (size_t)i * 1024 + c) = h;
            *(ushort4*)(Wq2 + (size_t)i * 1024 + 512 + c) = h;
        } else {
            *(ushort4*)(Wkh + off) = h;
        }
    } else {
        __shared__ u16 tile[64][70];
        const int bx = blockIdx.x - 512;                // 0..63
        const int t = threadIdx.x;
        const int d0 = (bx >> 3) * 64;
        const int c0 = (bx & 7) * 64;
        const int rr = t >> 4, col4 = (t & 15) * 4;
#pragma unroll
        for (int i = 0; i < 4; i++) {
            int row = i * 16 + rr;                      // d offset
            float4 v = *(const float4*)(wv + (size_t)(d0 + row) * 512 + c0 + col4);
            ushort4 h;
            h.x = f2h(v.x); h.y = f2h(v.y); h.z = f2h(v.z); h.w = f2h(v.w);
            *(ushort4*)&tile[row][col4] = h;
        }
        __syncthreads();
#pragma unroll
        for (int i = 0; i < 4; i++) {
            int crow = i * 16 + rr;                     // c offset
            ushort4 o;
            o.x = tile[col4 + 0][crow];
            o.y = tile[col4 + 1][crow];
            o.z = tile[col4 + 2][crow];
            o.w = tile[col4 + 3][crow];
            *(ushort4*)(WvT + (size_t)(c0 + crow) * 512 + d0 + col4) = o;
        }
    }
}

// ---------------------------------------------------------------------------
// k_convx: x f32 [B,512,4096] -> Xh f16 (same layout) + XT f16 [B,4096,512]
//          + rowsums s[b][c] = sum_n x  (f32 atomics, s pre-zeroed by k_prep)
// ---------------------------------------------------------------------------
__global__ __launch_bounds__(256) void k_convx(const float* __restrict__ x,
                                               u16* __restrict__ Xh,
                                               u16* __restrict__ XT,
                                               float* __restrict__ s)
{
    __shared__ u16 tile[64][70];
    const int t  = threadIdx.x;
    const int b  = blockIdx.z;
    const int c0 = blockIdx.y * 64;
    const int n0 = blockIdx.x * 64;
    const int rr   = t >> 4;
    const int col4 = (t & 15) * 4;

    const float* src = x + ((size_t)b * 512 + c0) * 4096 + n0;
    u16* xh = Xh + ((size_t)b * 512 + c0) * 4096 + n0;
#pragma unroll
    for (int i = 0; i < 4; i++) {
        int row = i * 16 + rr;
        float4 v = *(const float4*)(src + (size_t)row * 4096 + col4);
        ushort4 h;
        h.x = f2h(v.x); h.y = f2h(v.y); h.z = f2h(v.z); h.w = f2h(v.w);
        *(ushort4*)&tile[row][col4] = h;
        *(ushort4*)(xh + (size_t)row * 4096 + col4) = h;
        float p = v.x + v.y + v.z + v.w;
        p += __shfl_xor(p, 1); p += __shfl_xor(p, 2);
        p += __shfl_xor(p, 4); p += __shfl_xor(p, 8);
        if ((t & 15) == 0) atomicAdd(&s[b * 512 + c0 + row], p);
    }
    __syncthreads();
    u16* dst = XT + ((size_t)b * 4096 + n0) * 512 + c0;
#pragma unroll
    for (int i = 0; i < 4; i++) {
        int nrow = i * 16 + rr;
        ushort4 o;
        o.x = tile[col4 + 0][nrow];
        o.y = tile[col4 + 1][nrow];
        o.z = tile[col4 + 2][nrow];
        o.w = tile[col4 + 3][nrow];
        *(ushort4*)(dst + (size_t)nrow * 512 + col4) = o;
    }
}

// ---------------------------------------------------------------------------
// k_gram: symmetric Gram, XCD-swizzled.  Only the 10 upper-triangle 128^2
// tiles computed; off-diagonal tiles mirror-write the transposed tile.
// Gp[ks][b] = Xh[b, :, ks*1024:+1024] * (same)^T   split-K=4, f32 out.
// grid (320): flat -> swizzle so each XCD gets a contiguous 40-block chunk
// (~ one batch's Xh = 4MB = one XCD L2).
// ---------------------------------------------------------------------------
__global__ __launch_bounds__(256, 4) void k_gram(const u16* __restrict__ Xh,
                                                 float* __restrict__ Gp)
{
    __shared__ u16 smem[16384];          // 32 KB
    const int flat = blockIdx.x;         // 0..319
    const int swz  = (flat & 7) * 40 + (flat >> 3);   // bijective (320%8==0)
    const int tI = swz % 10;             // 0..9 upper-triangle tile
    const int bz = swz / 10;             // b*4 + ks
    const int tm = (tI >= 9) ? 3 : (tI >= 7) ? 2 : (tI >= 4) ? 1 : 0;
    const int rs = (tm == 0) ? 0 : (tm == 1) ? 4 : (tm == 2) ? 7 : 9;
    const int tn = tI - rs + tm;
    const int m0 = tm * 128, n0 = tn * 128;
    const int b  = bz >> 2, ks = bz & 3;

    const u16* Ap = Xh + (size_t)b * 512 * 4096 + (size_t)m0 * 4096 + ks * 1024;
    const u16* Bp = Xh + (size_t)b * 512 * 4096 + (size_t)n0 * 4096 + ks * 1024;

    f32x4 acc[4][4];
    zero_acc(acc);
    gemm_nt_f16(smem, Ap, 4096, Bp, 4096, 1024, acc);

    const int t = threadIdx.x, w = t >> 6, lane = t & 63;
    const int wm = (w >> 1) * 64, wn = (w & 1) * 64;
    const int cn = lane & 15, cq = lane >> 4;

    float* base = Gp + (size_t)(ks * 8 + b) * 512 * 512;
    float* outp = base + (size_t)m0 * 512 + n0;
#pragma unroll
    for (int mi = 0; mi < 4; mi++)
#pragma unroll
        for (int ni = 0; ni < 4; ni++)
#pragma unroll
            for (int r = 0; r < 4; r++) {
                int m = wm + mi * 16 + cq * 4 + r;
                int n = wn + ni * 16 + cn;
                outp[(size_t)m * 512 + n] = acc[mi][ni][r];
            }
    if (m0 != n0) {                      // mirror: G[n][m] = G[m][n]
        float* outT = base + (size_t)n0 * 512 + m0;
#pragma unroll
        for (int mi = 0; mi < 4; mi++)
#pragma unroll
            for (int ni = 0; ni < 4; ni++) {
                int mb = wm + mi * 16 + cq * 4;        // 4 consecutive m
                int n  = wn + ni * 16 + cn;
                float4 v4 = { acc[mi][ni][0], acc[mi][ni][1],
                              acc[mi][ni][2], acc[mi][ni][3] };
                *(float4*)(outT + (size_t)n * 512 + mb) = v4;
            }
    }
}

// ---------------------------------------------------------------------------
// k_gred: G = sum of 4 split-K partials; store hi/lo f16 pair
// Ghl[b][d][0:512] = hi(G[d][:]), [512:1024] = lo.
// blocks 0..127 additionally compute (fused k_uv):
//   ubar[b][i] = (Wq s_b)[i] + 4096*bq[i];  vv[b][j] = (Wk s_b)[j]
// ---------------------------------------------------------------------------
__global__ __launch_bounds__(256) void k_gred(const float* __restrict__ Gp,
                                              u16* __restrict__ Ghl,
                                              const float* __restrict__ wq,
                                              const float* __restrict__ bq,
                                              const float* __restrict__ wk,
                                              const float* __restrict__ s,
                                              float* __restrict__ ubar,
                                              float* __restrict__ vv)
{
    const size_t idx = ((size_t)blockIdx.x * 256 + threadIdx.x) * 4;
    const size_t st = (size_t)8 * 512 * 512;
    float4 g0 = *(const float4*)(Gp + idx);
    float4 g1 = *(const float4*)(Gp + idx + st);
    float4 g2 = *(const float4*)(Gp + idx + 2 * st);
    float4 g3 = *(const float4*)(Gp + idx + 3 * st);
    float gx = g0.x + g1.x + g2.x + g3.x;
    float gy = g0.y + g1.y + g2.y + g3.y;
    float gz = g0.z + g1.z + g2.z + g3.z;
    float gw = g0.w + g1.w + g2.w + g3.w;
    ushort4 hi, lo;
    hi.x = f2h(gx); lo.x = f2h(gx - h2f(hi.x));
    hi.y = f2h(gy); lo.y = f2h(gy - h2f(hi.y));
    hi.z = f2h(gz); lo.z = f2h(gz - h2f(hi.z));
    hi.w = f2h(gw); lo.w = f2h(gw - h2f(hi.w));
    const size_t row = idx >> 9;                 // b*512 + d
    const int c = (int)(idx & 511);
    *(ushort4*)(Ghl + row * 1024 + c) = hi;
    *(ushort4*)(Ghl + row * 1024 + 512 + c) = lo;

    if (blockIdx.x < 128) {                      // fused k_uv
        const int b = blockIdx.x >> 4;
        const int sub = blockIdx.x & 15;
        const int which = sub >> 3;
        const int r0 = (sub & 7) * 64;
        const int t = threadIdx.x;
        const int i = r0 + (t >> 2), l4 = t & 3;
        const float* W = which ? wk : wq;
        const float* sb = s + b * 512;
        float acc = 0.f;
#pragma unroll 4
        for (int k = 0; k < 32; k++) {
            int c2 = k * 16 + l4 * 4;
            float4 w4 = *(const float4*)(W + (size_t)i * 512 + c2);
            float4 s4 = *(const float4*)(sb + c2);
            acc += w4.x * s4.x + w4.y * s4.y + w4.z * s4.z + w4.w * s4.w;
        }
        acc += __shfl_xor(acc, 1);
        acc += __shfl_xor(acc, 2);
        if (l4 == 0) {
            if (which) vv[b * 512 + i] = acc;
            else       ubar[b * 512 + i] = acc + 4096.0f * bq[i];
        }
    }
}

// ---------------------------------------------------------------------------
// k_T: T[b] = [Wq|Wq] * Ghl[b]^T  (K=1024 hi/lo => f32-precise Wq*G), f16 out
// grid (4,4,8)
// ---------------------------------------------------------------------------
__global__ __launch_bounds__(256, 4) void k_T(const u16* __restrict__ Wq2,
                                              const u16* __restrict__ Ghl,
                                              u16* __restrict__ Tb)
{
    __shared__ u16 smem[16384];
    const int n0 = blockIdx.x * 128;
    const int m0 = blockIdx.y * 128;
    const int b  = blockIdx.z;

    const u16* Ap = Wq2 + (size_t)m0 * 1024;
    const u16* Bp = Ghl + (size_t)b * 512 * 1024 + (size_t)n0 * 1024;

    f32x4 acc[4][4];
    zero_acc(acc);
    gemm_nt_f16(smem, Ap, 1024, Bp, 1024, 1024, acc);

    const int t = threadIdx.x, w = t >> 6, lane = t & 63;
    const int wm = (w >> 1) * 64, wn = (w & 1) * 64;
    const int cn = lane & 15, cq = lane >> 4;

    u16* outp = Tb + ((size_t)b * 512 + m0) * 512 + n0;
#pragma unroll
    for (int mi = 0; mi < 4; mi++)
#pragma unroll
        for (int ni = 0; ni < 4; ni++)
#pragma unroll
            for (int r = 0; r < 4; r++) {
                int m = wm + mi * 16 + cq * 4 + r;
                int n = wn + ni * 16 + cn;
                outp[(size_t)m * 512 + n] = f2h(acc[mi][ni][r]);
            }
}

// ---------------------------------------------------------------------------
// k_S: fused  S = T*Wk^T + ubar*bk^T + bq*vv^T  -> row softmax -> P (f16)
//      also pbv[b][i] = sum_j P[i][j]*bv[j]
// Block = 16 rows x full 512 cols (rows complete -> in-block softmax).
// 4 waves; wave w owns cols [w*128, w*128+128).  grid (32, 8).
// ---------------------------------------------------------------------------
__global__ __launch_bounds__(256) void k_S(
    const u16* __restrict__ Tb, const u16* __restrict__ Wkh,
    const float* __restrict__ ubar, const float* __restrict__ vv,
    const float* __restrict__ bq, const float* __restrict__ bk,
    const float* __restrict__ bv,
    u16* __restrict__ P, float* __restrict__ pbv)
{
    __shared__ u16 smem[16896];          // As 16x32 (512) + Bs 512x32 (16384)
    __shared__ float redm[16][4];
    __shared__ float reds[16][4][2];
    u16* As = smem; u16* Bs = smem + 512;

    const int m0 = blockIdx.x * 16;
    const int b  = blockIdx.y;
    const int t = threadIdx.x, w = t >> 6, lane = t & 63;
    const int srow = lane >> 2;
    const int schunk = ((lane & 3) ^ ((srow >> 1) & 3)) * 8;
    const u16* gA = Tb + ((size_t)b * 512 + m0 + srow) * 512 + schunk;
    const int fr = lane & 15, fq = lane >> 4;
    const int fc = (fq ^ ((fr >> 1) & 3)) * 8;

    f32x4 acc[8];
#pragma unroll
    for (int i = 0; i < 8; i++) { f32x4 z = {0.f,0.f,0.f,0.f}; acc[i] = z; }

    for (int k0 = 0; k0 < 512; k0 += 32) {
        if (w == 0) async_copy16(gA + k0, As);
#pragma unroll
        for (int ii = 0; ii < 8; ii++) {
            int rbase = w * 128 + ii * 16;
            async_copy16(Wkh + (size_t)(rbase + srow) * 512 + k0 + schunk,
                         Bs + rbase * 32);
        }
        __syncthreads();
        f16x8 af = *(const f16x8*)(As + fr * 32 + fc);
#pragma unroll
        for (int ni = 0; ni < 8; ni++) {
            f16x8 bf = *(const f16x8*)(Bs + (w * 128 + ni * 16 + fr) * 32 + fc);
            acc[ni] = __builtin_amdgcn_mfma_f32_16x16x32_f16(af, bf, acc[ni], 0, 0, 0);
        }
        __syncthreads();
    }

    const int cn = lane & 15, cq = lane >> 4;
    float ub[4], bqr[4];
#pragma unroll
    for (int r = 0; r < 4; r++) {
        int i = m0 + cq * 4 + r;
        ub[r]  = ubar[b * 512 + i];
        bqr[r] = bq[i];
    }
    float vj[8], bkj[8], bvj[8];
#pragma unroll
    for (int ni = 0; ni < 8; ni++) {
        int j = w * 128 + ni * 16 + cn;
        vj[ni]  = vv[b * 512 + j];
        bkj[ni] = bk[j];
        bvj[ni] = bv[j];
    }
    float sv[8][4], mr[4];
#pragma unroll
    for (int r = 0; r < 4; r++) mr[r] = -1e30f;
#pragma unroll
    for (int ni = 0; ni < 8; ni++)
#pragma unroll
        for (int r = 0; r < 4; r++) {
            sv[ni][r] = acc[ni][r] + ub[r] * bkj[ni] + bqr[r] * vj[ni];
            mr[r] = fmaxf(mr[r], sv[ni][r]);
        }
#pragma unroll
    for (int r = 0; r < 4; r++)
        for (int o = 1; o < 16; o <<= 1) mr[r] = fmaxf(mr[r], __shfl_xor(mr[r], o));
    if (cn == 0) {
#pragma unroll
        for (int r = 0; r < 4; r++) redm[cq * 4 + r][w] = mr[r];
    }
    __syncthreads();
#pragma unroll
    for (int r = 0; r < 4; r++) {
        int row = cq * 4 + r;
        mr[r] = fmaxf(fmaxf(redm[row][0], redm[row][1]),
                      fmaxf(redm[row][2], redm[row][3]));
    }
    float e[8][4], se[4], sebv[4];
#pragma unroll
    for (int r = 0; r < 4; r++) { se[r] = 0.f; sebv[r] = 0.f; }
#pragma unroll
    for (int ni = 0; ni < 8; ni++)
#pragma unroll
        for (int r = 0; r < 4; r++) {
            float ev = __expf(sv[ni][r] - mr[r]);
            e[ni][r] = ev;
            se[r]   += ev;
            sebv[r] += ev * bvj[ni];
        }
#pragma unroll
    for (int r = 0; r < 4; r++)
        for (int o = 1; o < 16; o <<= 1) {
            se[r]   += __shfl_xor(se[r], o);
            sebv[r] += __shfl_xor(sebv[r], o);
        }
    if (cn == 0) {
#pragma unroll
        for (int r = 0; r < 4; r++) {
            reds[cq * 4 + r][w][0] = se[r];
            reds[cq * 4 + r][w][1] = sebv[r];
        }
    }
    __syncthreads();
#pragma unroll
    for (int r = 0; r < 4; r++) {
        int row = cq * 4 + r;
        float S  = reds[row][0][0] + reds[row][1][0] + reds[row][2][0] + reds[row][3][0];
        float SB = reds[row][0][1] + reds[row][1][1] + reds[row][2][1] + reds[row][3][1];
        float inv = 1.0f / S;
#pragma unroll
        for (int ni = 0; ni < 8; ni++)
            P[((size_t)b * 512 + m0 + row) * 512 + w * 128 + ni * 16 + cn] =
                f2h(e[ni][r] * inv);
        if (w == 0 && cn == 0) pbv[b * 512 + m0 + row] = SB * inv;
    }
}

// ---------------------------------------------------------------------------
// k_M: M2[b] = P[b] * Wv  (contraction over P cols / Wv rows => B = WvT), f16
// grid (4,4,8)
// ---------------------------------------------------------------------------
__global__ __launch_bounds__(256, 4) void k_M(const u16* __restrict__ P,
                                              const u16* __restrict__ WvT,
                                              u16* __restrict__ M2)
{
    __shared__ u16 smem[16384];
    const int n0 = blockIdx.x * 128;
    const int m0 = blockIdx.y * 128;
    const int b  = blockIdx.z;

    const u16* Ap = P + (size_t)b * 512 * 512 + (size_t)m0 * 512;
    const u16* Bp = WvT + (size_t)n0 * 512;

    f32x4 acc[4][4];
    zero_acc(acc);
    gemm_nt_f16(smem, Ap, 512, Bp, 512, 512, acc);

    const int t = threadIdx.x, w = t >> 6, lane = t & 63;
    const int wm = (w >> 1) * 64, wn = (w & 1) * 64;
    const int cn = lane & 15, cq = lane >> 4;

    u16* outp = M2 + ((size_t)b * 512 + m0) * 512 + n0;
#pragma unroll
    for (int mi = 0; mi < 4; mi++)
#pragma unroll
        for (int ni = 0; ni < 4; ni++)
#pragma unroll
            for (int r = 0; r < 4; r++) {
                int m = wm + mi * 16 + cq * 4 + r;
                int n = wn + ni * 16 + cn;
                outp[(size_t)m * 512 + n] = f2h(acc[mi][ni][r]);
            }
}

// ---------------------------------------------------------------------------
// k_out: out = M2 * X + pbv*1^T + x_res   (residual from Xh f16), f32 out
// grid (1024) XCD-swizzled: each XCD owns one batch (XT slice 4MB = L2).
// ---------------------------------------------------------------------------
__global__ __launch_bounds__(256, 4) void k_out(const u16* __restrict__ M2,
                                                const u16* __restrict__ XT,
                                                const u16* __restrict__ Xh,
                                                const float* __restrict__ pbv,
                                                float* __restrict__ out)
{
    __shared__ u16 smem[16384];
    const int flat = blockIdx.x;                  // 0..1023
    const int swz  = (flat & 7) * 128 + (flat >> 3);   // bijective (1024%8==0)
    const int n0 = (swz & 31) * 128;
    const int m0 = ((swz >> 5) & 3) * 128;
    const int b  = swz >> 7;

    const u16* Ap = M2 + (size_t)b * 512 * 512 + (size_t)m0 * 512;
    const u16* Bp = XT + (size_t)b * 4096 * 512 + (size_t)n0 * 512;

    f32x4 acc[4][4];
    zero_acc(acc);
    gemm_nt_f16(smem, Ap, 512, Bp, 512, 512, acc);

    const int t = threadIdx.x, w = t >> 6, lane = t & 63;
    const int wm = (w >> 1) * 64, wn = (w & 1) * 64;
    const int cn = lane & 15, cq = lane >> 4;

#pragma unroll
    for (int mi = 0; mi < 4; mi++)
#pragma unroll
        for (int ni = 0; ni < 4; ni++)
#pragma unroll
            for (int r = 0; r < 4; r++) {
                int m = m0 + wm + mi * 16 + cq * 4 + r;
                int n = n0 + wn + ni * 16 + cn;
                size_t idx = ((size_t)b * 512 + m) * 4096 + n;
                out[idx] = acc[mi][ni][r] + pbv[b * 512 + m] + h2f(Xh[idx]);
            }
}

// ---------------------------------------------------------------------------
// ws layout (bytes), high-water ~118 MiB:
//   Wq2  [512][1024] f16   @ 0          (1048576)
//   Wkh  [512][512]  f16   @ 1048576    (524288)
//   WvT  [512][512]  f16   @ 1572864    (524288)
//   s    [8][512]    f32   @ 2097152    (16384)
//   ubar [8][512]    f32   @ 2113536    (16384)
//   vv   [8][512]    f32   @ 2129920    (16384)
//   pbv  [8][512]    f32   @ 2146304    (16384)
//   Xh   [8][512][4096] f16 @ 2162688   (33554432)
//   XT   [8][4096][512] f16 @ 35717120  (33554432)
//   Gp   [4][8][512][512] f32 @ 69271552 (33554432)
//   Ghl  [8][512][1024] f16 @ 102825984 (8388608)
//   Tb   [8][512][512] f16  @ 111214592 (4194304)
//   P    [8][512][512] f16  @ 115408896 (4194304)
//   M2   [8][512][512] f16  @ 119603200 (4194304)
// ---------------------------------------------------------------------------
extern "C" void kernel_launch(void* const* d_in, const int* in_sizes, int n_in,
                              void* d_out, int out_size, void* d_ws, size_t ws_size,
                              hipStream_t stream)
{
    const float* x  = (const float*)d_in[0];
    const float* wq = (const float*)d_in[1];
    const float* bq = (const float*)d_in[2];
    const float* wk = (const float*)d_in[3];
    const float* bk = (const float*)d_in[4];
    const float* wv = (const float*)d_in[5];
    const float* bv = (const float*)d_in[6];
    float* out = (float*)d_out;

    char* ws = (char*)d_ws;
    u16*   Wq2  = (u16*)(ws);
    u16*   Wkh  = (u16*)(ws + 1048576);
    u16*   WvT  = (u16*)(ws + 1572864);
    float* s    = (float*)(ws + 2097152);
    float* ubar = (float*)(ws + 2113536);
    float* vv   = (float*)(ws + 2129920);
    float* pbv  = (float*)(ws + 2146304);
    u16*   Xh   = (u16*)(ws + 2162688);
    u16*   XT   = (u16*)(ws + 35717120);
    float* Gp   = (float*)(ws + 69271552);
    u16*   Ghl  = (u16*)(ws + 102825984);
    u16*   Tb   = (u16*)(ws + 111214592);
    u16*   P    = (u16*)(ws + 115408896);
    u16*   M2   = (u16*)(ws + 119603200);

    k_prep<<<dim3(576), dim3(256), 0, stream>>>(wq, wk, wv, Wq2, Wkh, WvT, s);
    k_convx<<<dim3(64, 8, 8), dim3(256), 0, stream>>>(x, Xh, XT, s);
    k_gram<<<dim3(320), dim3(256), 0, stream>>>(Xh, Gp);
    k_gred<<<dim3(2048), dim3(256), 0, stream>>>(Gp, Ghl, wq, bq, wk, s, ubar, vv);
    k_T<<<dim3(4, 4, 8), dim3(256), 0, stream>>>(Wq2, Ghl, Tb);
    k_S<<<dim3(32, 8), dim3(256), 0, stream>>>(Tb, Wkh, ubar, vv, bq, bk, bv, P, pbv);
    k_M<<<dim3(4, 4, 8), dim3(256), 0, stream>>>(P, WvT, M2);
    k_out<<<dim3(1024), dim3(256), 0, stream>>>(M2, XT, Xh, pbv, out);
}

// Round 7
// 247.665 us; speedup vs baseline: 1.0701x; 1.0095x over previous
//
#include <hip/hip_runtime.h>
#include <cstdint>

typedef unsigned short u16;
typedef unsigned int   u32;
typedef _Float16 f16;

typedef __attribute__((ext_vector_type(8))) _Float16 f16x8;   // 8 fp16 = 4 VGPRs
typedef __attribute__((ext_vector_type(4))) float    f32x4;   // MFMA accumulator

__device__ __forceinline__ u16 f2h(float f) {
    union { f16 h; u16 u; } c; c.h = (f16)f; return c.u;      // v_cvt_f16_f32 RTNE
}
__device__ __forceinline__ float h2f(u16 u) {
    union { u16 u; f16 h; } c; c.u = u; return (float)c.h;
}

// async global->LDS, 16B per lane; LDS dest = wave-uniform base + lane*16
__device__ __forceinline__ void async_copy16(const u16* g, u16* lds) {
    __builtin_amdgcn_global_load_lds(
        (const __attribute__((address_space(1))) void*)g,
        (__attribute__((address_space(3))) void*)lds,
        16, 0, 0);
}

// ---------------------------------------------------------------------------
// fp16 NT GEMM core, BK=64 as two 32-wide sub-tiles (proven r3 structure):
//   C[128,128] += A[128,K] * B[128,K]^T, K contiguous both.
// 256 thr = 4 waves (2x2), each wave 64x64 = 4x4 MFMA 16x16x32.
// LDS 32 KB: As0@0, As1@4096, Bs0@8192, Bs1@12288 (u16), each [128][32]
// XOR-swizzled (0 bank conflicts measured).  stage -> sync -> 2x compute -> sync.
// ---------------------------------------------------------------------------
__device__ __forceinline__ void gemm_nt_f16(
    u16* smem, const u16* __restrict__ A, int lda,
    const u16* __restrict__ B, int ldb, int K, f32x4 acc[4][4])
{
    const int t = threadIdx.x, w = t >> 6, lane = t & 63;
    const int srow = lane >> 2;                    // 0..15 within chunk
    const int skc  = (((lane & 3) ^ ((lane >> 3) & 3)) * 8);  // swizzled
    const int ra0 = (w*2+0)*16 + srow, ra1 = (w*2+1)*16 + srow;
    const u16* gA0 = A + (size_t)ra0 * lda + skc;
    const u16* gA1 = A + (size_t)ra1 * lda + skc;
    const u16* gB0 = B + (size_t)ra0 * ldb + skc;
    const u16* gB1 = B + (size_t)ra1 * ldb + skc;
    u16* lA0 = smem + (w*2+0)*512;                 // row base within a 32-wide tile
    u16* lA1 = smem + (w*2+1)*512;
    const int fr = lane & 15, fq = lane >> 4;
    const int fc = (fq ^ ((fr >> 1) & 3)) * 8;     // swizzled fragment chunk
    const int wm = (w >> 1) * 64, wn = (w & 1) * 64;
    const int fAo = (wm + fr) * 32 + fc;
    const int fBo = (wn + fr) * 32 + fc;

    for (int k0 = 0; k0 < K; k0 += 64) {
        async_copy16(gA0 + k0,      lA0);
        async_copy16(gA1 + k0,      lA1);
        async_copy16(gA0 + k0 + 32, lA0 + 4096);
        async_copy16(gA1 + k0 + 32, lA1 + 4096);
        async_copy16(gB0 + k0,      lA0 + 8192);
        async_copy16(gB1 + k0,      lA1 + 8192);
        async_copy16(gB0 + k0 + 32, lA0 + 12288);
        async_copy16(gB1 + k0 + 32, lA1 + 12288);
        __syncthreads();
        {   // k-sub 0
            f16x8 af[4], bf[4];
#pragma unroll
            for (int i = 0; i < 4; i++) af[i] = *(const f16x8*)(smem + fAo + i * 512);
#pragma unroll
            for (int i = 0; i < 4; i++) bf[i] = *(const f16x8*)(smem + 8192 + fBo + i * 512);
#pragma unroll
            for (int mi = 0; mi < 4; mi++)
#pragma unroll
                for (int ni = 0; ni < 4; ni++)
                    acc[mi][ni] = __builtin_amdgcn_mfma_f32_16x16x32_f16(
                        af[mi], bf[ni], acc[mi][ni], 0, 0, 0);
        }
        {   // k-sub 1
            f16x8 af[4], bf[4];
#pragma unroll
            for (int i = 0; i < 4; i++) af[i] = *(const f16x8*)(smem + 4096 + fAo + i * 512);
#pragma unroll
            for (int i = 0; i < 4; i++) bf[i] = *(const f16x8*)(smem + 12288 + fBo + i * 512);
#pragma unroll
            for (int mi = 0; mi < 4; mi++)
#pragma unroll
                for (int ni = 0; ni < 4; ni++)
                    acc[mi][ni] = __builtin_amdgcn_mfma_f32_16x16x32_f16(
                        af[mi], bf[ni], acc[mi][ni], 0, 0, 0);
        }
        __syncthreads();
    }
}

__device__ __forceinline__ void zero_acc(f32x4 acc[4][4]) {
#pragma unroll
    for (int i = 0; i < 4; i++)
#pragma unroll
        for (int j = 0; j < 4; j++) {
            f32x4 z = {0.f, 0.f, 0.f, 0.f};
            acc[i][j] = z;
        }
}

// ---------------------------------------------------------------------------
// k_convx: x f32 [B,512,4096] -> Xh f16 (same layout) + XT f16 [B,4096,512]
//          + rowsums s[b][c] = sum_n x  (f32 atomics, s zeroed via memset)
// ---------------------------------------------------------------------------
__global__ __launch_bounds__(256) void k_convx(const float* __restrict__ x,
                                               u16* __restrict__ Xh,
                                               u16* __restrict__ XT,
                                               float* __restrict__ s)
{
    __shared__ u16 tile[64][70];
    const int t  = threadIdx.x;
    const int b  = blockIdx.z;
    const int c0 = blockIdx.y * 64;
    const int n0 = blockIdx.x * 64;
    const int rr   = t >> 4;
    const int col4 = (t & 15) * 4;

    const float* src = x + ((size_t)b * 512 + c0) * 4096 + n0;
    u16* xh = Xh + ((size_t)b * 512 + c0) * 4096 + n0;
#pragma unroll
    for (int i = 0; i < 4; i++) {
        int row = i * 16 + rr;
        float4 v = *(const float4*)(src + (size_t)row * 4096 + col4);
        ushort4 h;
        h.x = f2h(v.x); h.y = f2h(v.y); h.z = f2h(v.z); h.w = f2h(v.w);
        *(ushort4*)&tile[row][col4] = h;
        *(ushort4*)(xh + (size_t)row * 4096 + col4) = h;
        float p = v.x + v.y + v.z + v.w;
        p += __shfl_xor(p, 1); p += __shfl_xor(p, 2);
        p += __shfl_xor(p, 4); p += __shfl_xor(p, 8);
        if ((t & 15) == 0) atomicAdd(&s[b * 512 + c0 + row], p);
    }
    __syncthreads();
    u16* dst = XT + ((size_t)b * 4096 + n0) * 512 + c0;
#pragma unroll
    for (int i = 0; i < 4; i++) {
        int nrow = i * 16 + rr;
        ushort4 o;
        o.x = tile[col4 + 0][nrow];
        o.y = tile[col4 + 1][nrow];
        o.z = tile[col4 + 2][nrow];
        o.w = tile[col4 + 3][nrow];
        *(ushort4*)(dst + (size_t)nrow * 512 + col4) = o;
    }
}

// ---------------------------------------------------------------------------
// k_gram: blocks 0..319: symmetric Gram (XCD-swizzled, 10 upper-tri tiles,
//                        mirror-write off-diagonals).  split-K=4, f32 out.
//         blocks 320..831: prep Wq -> [Wq|Wq] f16, Wk -> f16   (fused k_prep)
//         blocks 832..895: prep WvT[c][d] = f16(wv[d][c])
// ---------------------------------------------------------------------------
__global__ __launch_bounds__(256, 4) void k_gram(const u16* __restrict__ Xh,
                                                 float* __restrict__ Gp,
                                                 const float* __restrict__ wq,
                                                 const float* __restrict__ wk,
                                                 const float* __restrict__ wv,
                                                 u16* __restrict__ Wq2,
                                                 u16* __restrict__ Wkh,
                                                 u16* __restrict__ WvT)
{
    __shared__ u16 smem[16384];          // 32 KB (gemm stage / prep tile alias)
    const int bxx = blockIdx.x;
    if (bxx < 320) {
        const int swz  = (bxx & 7) * 40 + (bxx >> 3);   // bijective (320%8==0)
        const int tI = swz % 10;             // 0..9 upper-triangle tile
        const int bz = swz / 10;             // b*4 + ks
        const int tm = (tI >= 9) ? 3 : (tI >= 7) ? 2 : (tI >= 4) ? 1 : 0;
        const int rs = (tm == 0) ? 0 : (tm == 1) ? 4 : (tm == 2) ? 7 : 9;
        const int tn = tI - rs + tm;
        const int m0 = tm * 128, n0 = tn * 128;
        const int b  = bz >> 2, ks = bz & 3;

        const u16* Ap = Xh + (size_t)b * 512 * 4096 + (size_t)m0 * 4096 + ks * 1024;
        const u16* Bp = Xh + (size_t)b * 512 * 4096 + (size_t)n0 * 4096 + ks * 1024;

        f32x4 acc[4][4];
        zero_acc(acc);
        gemm_nt_f16(smem, Ap, 4096, Bp, 4096, 1024, acc);

        const int t = threadIdx.x, w = t >> 6, lane = t & 63;
        const int wm = (w >> 1) * 64, wn = (w & 1) * 64;
        const int cn = lane & 15, cq = lane >> 4;

        float* base = Gp + (size_t)(ks * 8 + b) * 512 * 512;
        float* outp = base + (size_t)m0 * 512 + n0;
#pragma unroll
        for (int mi = 0; mi < 4; mi++)
#pragma unroll
            for (int ni = 0; ni < 4; ni++)
#pragma unroll
                for (int r = 0; r < 4; r++) {
                    int m = wm + mi * 16 + cq * 4 + r;
                    int n = wn + ni * 16 + cn;
                    outp[(size_t)m * 512 + n] = acc[mi][ni][r];
                }
        if (m0 != n0) {                      // mirror: G[n][m] = G[m][n]
            float* outT = base + (size_t)n0 * 512 + m0;
#pragma unroll
            for (int mi = 0; mi < 4; mi++)
#pragma unroll
                for (int ni = 0; ni < 4; ni++) {
                    int mb = wm + mi * 16 + cq * 4;        // 4 consecutive m
                    int n  = wn + ni * 16 + cn;
                    float4 v4 = { acc[mi][ni][0], acc[mi][ni][1],
                                  acc[mi][ni][2], acc[mi][ni][3] };
                    *(float4*)(outT + (size_t)n * 512 + mb) = v4;
                }
        }
    } else if (bxx < 832) {
        const int t = (bxx - 320) * 256 + threadIdx.x;  // 0..131071
        const int e = t * 4;
        const int sel = e >> 18;                        // 0: wq, 1: wk
        const int off = e & 262143;
        const float* src = sel ? wk : wq;
        float4 v = *(const float4*)(src + off);
        ushort4 h;
        h.x = f2h(v.x); h.y = f2h(v.y); h.z = f2h(v.z); h.w = f2h(v.w);
        if (sel == 0) {
            int i = off >> 9, c = off & 511;
            *(ushort4*)(Wq2 + (size_t)i * 1024 + c) = h;
            *(ushort4*)(Wq2 + (size_t)i * 1024 + 512 + c) = h;
        } else {
            *(ushort4*)(Wkh + off) = h;
        }
    } else {
        u16 (*tile)[70] = (u16(*)[70])smem;             // 64x70 fits in 16384 u16
        const int bx = bxx - 832;                       // 0..63
        const int t = threadIdx.x;
        const int d0 = (bx >> 3) * 64;
        const int c0 = (bx & 7) * 64;
        const int rr = t >> 4, col4 = (t & 15) * 4;
#pragma unroll
        for (int i = 0; i < 4; i++) {
            int row = i * 16 + rr;                      // d offset
            float4 v = *(const float4*)(wv + (size_t)(d0 + row) * 512 + c0 + col4);
            ushort4 h;
            h.x = f2h(v.x); h.y = f2h(v.y); h.z = f2h(v.z); h.w = f2h(v.w);
            *(ushort4*)&tile[row][col4] = h;
        }
        __syncthreads();
#pragma unroll
        for (int i = 0; i < 4; i++) {
            int crow = i * 16 + rr;                     // c offset
            ushort4 o;
            o.x = tile[col4 + 0][crow];
            o.y = tile[col4 + 1][crow];
            o.z = tile[col4 + 2][crow];
            o.w = tile[col4 + 3][crow];
            *(ushort4*)(WvT + (size_t)(c0 + crow) * 512 + d0 + col4) = o;
        }
    }
}

// ---------------------------------------------------------------------------
// k_gred: G = sum of 4 split-K partials; store hi/lo f16 pair
// Ghl[b][d][0:512] = hi(G[d][:]), [512:1024] = lo.
// blocks 0..127 additionally compute (fused k_uv):
//   ubar[b][i] = (Wq s_b)[i] + 4096*bq[i];  vv[b][j] = (Wk s_b)[j]
// ---------------------------------------------------------------------------
__global__ __launch_bounds__(256) void k_gred(const float* __restrict__ Gp,
                                              u16* __restrict__ Ghl,
                                              const float* __restrict__ wq,
                                              const float* __restrict__ bq,
                                              const float* __restrict__ wk,
                                              const float* __restrict__ s,
                                              float* __restrict__ ubar,
                                              float* __restrict__ vv)
{
    const size_t idx = ((size_t)blockIdx.x * 256 + threadIdx.x) * 4;
    const size_t st = (size_t)8 * 512 * 512;
    float4 g0 = *(const float4*)(Gp + idx);
    float4 g1 = *(const float4*)(Gp + idx + st);
    float4 g2 = *(const float4*)(Gp + idx + 2 * st);
    float4 g3 = *(const float4*)(Gp + idx + 3 * st);
    float gx = g0.x + g1.x + g2.x + g3.x;
    float gy = g0.y + g1.y + g2.y + g3.y;
    float gz = g0.z + g1.z + g2.z + g3.z;
    float gw = g0.w + g1.w + g2.w + g3.w;
    ushort4 hi, lo;
    hi.x = f2h(gx); lo.x = f2h(gx - h2f(hi.x));
    hi.y = f2h(gy); lo.y = f2h(gy - h2f(hi.y));
    hi.z = f2h(gz); lo.z = f2h(gz - h2f(hi.z));
    hi.w = f2h(gw); lo.w = f2h(gw - h2f(hi.w));
    const size_t row = idx >> 9;                 // b*512 + d
    const int c = (int)(idx & 511);
    *(ushort4*)(Ghl + row * 1024 + c) = hi;
    *(ushort4*)(Ghl + row * 1024 + 512 + c) = lo;

    if (blockIdx.x < 128) {                      // fused k_uv
        const int b = blockIdx.x >> 4;
        const int sub = blockIdx.x & 15;
        const int which = sub >> 3;
        const int r0 = (sub & 7) * 64;
        const int t = threadIdx.x;
        const int i = r0 + (t >> 2), l4 = t & 3;
        const float* W = which ? wk : wq;
        const float* sb = s + b * 512;
        float acc = 0.f;
#pragma unroll 4
        for (int k = 0; k < 32; k++) {
            int c2 = k * 16 + l4 * 4;
            float4 w4 = *(const float4*)(W + (size_t)i * 512 + c2);
            float4 s4 = *(const float4*)(sb + c2);
            acc += w4.x * s4.x + w4.y * s4.y + w4.z * s4.z + w4.w * s4.w;
        }
        acc += __shfl_xor(acc, 1);
        acc += __shfl_xor(acc, 2);
        if (l4 == 0) {
            if (which) vv[b * 512 + i] = acc;
            else       ubar[b * 512 + i] = acc + 4096.0f * bq[i];
        }
    }
}

// ---------------------------------------------------------------------------
// k_T: T[b] = [Wq|Wq] * Ghl[b]^T  (K=1024 hi/lo => f32-precise Wq*G), f16 out
// grid (4,4,8)
// ---------------------------------------------------------------------------
__global__ __launch_bounds__(256, 4) void k_T(const u16* __restrict__ Wq2,
                                              const u16* __restrict__ Ghl,
                                              u16* __restrict__ Tb)
{
    __shared__ u16 smem[16384];
    const int n0 = blockIdx.x * 128;
    const int m0 = blockIdx.y * 128;
    const int b  = blockIdx.z;

    const u16* Ap = Wq2 + (size_t)m0 * 1024;
    const u16* Bp = Ghl + (size_t)b * 512 * 1024 + (size_t)n0 * 1024;

    f32x4 acc[4][4];
    zero_acc(acc);
    gemm_nt_f16(smem, Ap, 1024, Bp, 1024, 1024, acc);

    const int t = threadIdx.x, w = t >> 6, lane = t & 63;
    const int wm = (w >> 1) * 64, wn = (w & 1) * 64;
    const int cn = lane & 15, cq = lane >> 4;

    u16* outp = Tb + ((size_t)b * 512 + m0) * 512 + n0;
#pragma unroll
    for (int mi = 0; mi < 4; mi++)
#pragma unroll
        for (int ni = 0; ni < 4; ni++)
#pragma unroll
            for (int r = 0; r < 4; r++) {
                int m = wm + mi * 16 + cq * 4 + r;
                int n = wn + ni * 16 + cn;
                outp[(size_t)m * 512 + n] = f2h(acc[mi][ni][r]);
            }
}

// ---------------------------------------------------------------------------
// k_S: fused  S = T*Wk^T + ubar*bk^T + bq*vv^T  -> row softmax -> P (f16)
//      also pbv[b][i] = sum_j P[i][j]*bv[j]
// Block = 16 rows x full 512 cols, 512 threads = 8 waves; wave w owns cols
// [w*64, w*64+64).  BK=32, single-buffered.
// LDS: As[512] (1KB) + Bs[512*32] (32KB) + red (1.5KB) ~ 35KB.  grid (32, 8).
// ---------------------------------------------------------------------------
__global__ __launch_bounds__(512) void k_S(
    const u16* __restrict__ Tb, const u16* __restrict__ Wkh,
    const float* __restrict__ ubar, const float* __restrict__ vv,
    const float* __restrict__ bq, const float* __restrict__ bk,
    const float* __restrict__ bv,
    u16* __restrict__ P, float* __restrict__ pbv)
{
    __shared__ u16 As[512];
    __shared__ u16 Bs[16384];
    __shared__ float redm[16][8];
    __shared__ float reds[16][8][2];

    const int m0 = blockIdx.x * 16;
    const int b  = blockIdx.y;
    const int t = threadIdx.x, w = t >> 6, lane = t & 63;
    const int srow = lane >> 2;
    const int schunk = ((lane & 3) ^ ((srow >> 1) & 3)) * 8;
    const u16* gA = Tb + ((size_t)b * 512 + m0 + srow) * 512 + schunk;
    const int fr = lane & 15, fq = lane >> 4;
    const int fc = (fq ^ ((fr >> 1) & 3)) * 8;

    f32x4 acc[4];
#pragma unroll
    for (int i = 0; i < 4; i++) { f32x4 z = {0.f,0.f,0.f,0.f}; acc[i] = z; }

    for (int k0 = 0; k0 < 512; k0 += 32) {
        if (w == 0) async_copy16(gA + k0, As);
#pragma unroll
        for (int ii = 0; ii < 4; ii++) {
            int rbase = w * 64 + ii * 16;
            async_copy16(Wkh + (size_t)(rbase + srow) * 512 + k0 + schunk,
                         Bs + rbase * 32);
        }
        __syncthreads();
        f16x8 af = *(const f16x8*)(As + fr * 32 + fc);
#pragma unroll
        for (int ni = 0; ni < 4; ni++) {
            f16x8 bf = *(const f16x8*)(Bs + (w * 64 + ni * 16 + fr) * 32 + fc);
            acc[ni] = __builtin_amdgcn_mfma_f32_16x16x32_f16(af, bf, acc[ni], 0, 0, 0);
        }
        __syncthreads();
    }

    const int cn = lane & 15, cq = lane >> 4;
    float ub[4], bqr[4];
#pragma unroll
    for (int r = 0; r < 4; r++) {
        int i = m0 + cq * 4 + r;
        ub[r]  = ubar[b * 512 + i];
        bqr[r] = bq[i];
    }
    float vj[4], bkj[4], bvj[4];
#pragma unroll
    for (int ni = 0; ni < 4; ni++) {
        int j = w * 64 + ni * 16 + cn;
        vj[ni]  = vv[b * 512 + j];
        bkj[ni] = bk[j];
        bvj[ni] = bv[j];
    }
    float sv[4][4], mr[4];
#pragma unroll
    for (int r = 0; r < 4; r++) mr[r] = -1e30f;
#pragma unroll
    for (int ni = 0; ni < 4; ni++)
#pragma unroll
        for (int r = 0; r < 4; r++) {
            sv[ni][r] = acc[ni][r] + ub[r] * bkj[ni] + bqr[r] * vj[ni];
            mr[r] = fmaxf(mr[r], sv[ni][r]);
        }
#pragma unroll
    for (int r = 0; r < 4; r++)
        for (int o = 1; o < 16; o <<= 1) mr[r] = fmaxf(mr[r], __shfl_xor(mr[r], o));
    if (cn == 0) {
#pragma unroll
        for (int r = 0; r < 4; r++) redm[cq * 4 + r][w] = mr[r];
    }
    __syncthreads();
#pragma unroll
    for (int r = 0; r < 4; r++) {
        int row = cq * 4 + r;
        float m01 = fmaxf(redm[row][0], redm[row][1]);
        float m23 = fmaxf(redm[row][2], redm[row][3]);
        float m45 = fmaxf(redm[row][4], redm[row][5]);
        float m67 = fmaxf(redm[row][6], redm[row][7]);
        mr[r] = fmaxf(fmaxf(m01, m23), fmaxf(m45, m67));
    }
    float e[4][4], se[4], sebv[4];
#pragma unroll
    for (int r = 0; r < 4; r++) { se[r] = 0.f; sebv[r] = 0.f; }
#pragma unroll
    for (int ni = 0; ni < 4; ni++)
#pragma unroll
        for (int r = 0; r < 4; r++) {
            float ev = __expf(sv[ni][r] - mr[r]);
            e[ni][r] = ev;
            se[r]   += ev;
            sebv[r] += ev * bvj[ni];
        }
#pragma unroll
    for (int r = 0; r < 4; r++)
        for (int o = 1; o < 16; o <<= 1) {
            se[r]   += __shfl_xor(se[r], o);
            sebv[r] += __shfl_xor(sebv[r], o);
        }
    if (cn == 0) {
#pragma unroll
        for (int r = 0; r < 4; r++) {
            reds[cq * 4 + r][w][0] = se[r];
            reds[cq * 4 + r][w][1] = sebv[r];
        }
    }
    __syncthreads();
#pragma unroll
    for (int r = 0; r < 4; r++) {
        int row = cq * 4 + r;
        float S = 0.f, SB = 0.f;
#pragma unroll
        for (int ww = 0; ww < 8; ww++) {
            S  += reds[row][ww][0];
            SB += reds[row][ww][1];
        }
        float inv = 1.0f / S;
#pragma unroll
        for (int ni = 0; ni < 4; ni++)
            P[((size_t)b * 512 + m0 + row) * 512 + w * 64 + ni * 16 + cn] =
                f2h(e[ni][r] * inv);
        if (w == 0 && cn == 0) pbv[b * 512 + m0 + row] = SB * inv;
    }
}

// ---------------------------------------------------------------------------
// k_M: M2[b] = P[b] * Wv  (contraction over P cols / Wv rows => B = WvT), f16
// grid (4,4,8)
// ---------------------------------------------------------------------------
__global__ __launch_bounds__(256, 4) void k_M(const u16* __restrict__ P,
                                              const u16* __restrict__ WvT,
                                              u16* __restrict__ M2)
{
    __shared__ u16 smem[16384];
    const int n0 = blockIdx.x * 128;
    const int m0 = blockIdx.y * 128;
    const int b  = blockIdx.z;

    const u16* Ap = P + (size_t)b * 512 * 512 + (size_t)m0 * 512;
    const u16* Bp = WvT + (size_t)n0 * 512;

    f32x4 acc[4][4];
    zero_acc(acc);
    gemm_nt_f16(smem, Ap, 512, Bp, 512, 512, acc);

    const int t = threadIdx.x, w = t >> 6, lane = t & 63;
    const int wm = (w >> 1) * 64, wn = (w & 1) * 64;
    const int cn = lane & 15, cq = lane >> 4;

    u16* outp = M2 + ((size_t)b * 512 + m0) * 512 + n0;
#pragma unroll
    for (int mi = 0; mi < 4; mi++)
#pragma unroll
        for (int ni = 0; ni < 4; ni++)
#pragma unroll
            for (int r = 0; r < 4; r++) {
                int m = wm + mi * 16 + cq * 4 + r;
                int n = wn + ni * 16 + cn;
                outp[(size_t)m * 512 + n] = f2h(acc[mi][ni][r]);
            }
}

// ---------------------------------------------------------------------------
// k_out: out = M2 * X + pbv*1^T + x_res   (residual from Xh f16), f32 out
// grid (1024) XCD-swizzled: each XCD owns one batch (XT slice 4MB = L2).
// ---------------------------------------------------------------------------
__global__ __launch_bounds__(256, 4) void k_out(const u16* __restrict__ M2,
                                                const u16* __restrict__ XT,
                                                const u16* __restrict__ Xh,
                                                const float* __restrict__ pbv,
                                                float* __restrict__ out)
{
    __shared__ u16 smem[16384];
    const int flat = blockIdx.x;                  // 0..1023
    const int swz  = (flat & 7) * 128 + (flat >> 3);   // bijective (1024%8==0)
    const int n0 = (swz & 31) * 128;
    const int m0 = ((swz >> 5) & 3) * 128;
    const int b  = swz >> 7;

    const u16* Ap = M2 + (size_t)b * 512 * 512 + (size_t)m0 * 512;
    const u16* Bp = XT + (size_t)b * 4096 * 512 + (size_t)n0 * 512;

    f32x4 acc[4][4];
    zero_acc(acc);
    gemm_nt_f16(smem, Ap, 512, Bp, 512, 512, acc);

    const int t = threadIdx.x, w = t >> 6, lane = t & 63;
    const int wm = (w >> 1) * 64, wn = (w & 1) * 64;
    const int cn = lane & 15, cq = lane >> 4;

#pragma unroll
    for (int mi = 0; mi < 4; mi++)
#pragma unroll
        for (int ni = 0; ni < 4; ni++)
#pragma unroll
            for (int r = 0; r < 4; r++) {
                int m = m0 + wm + mi * 16 + cq * 4 + r;
                int n = n0 + wn + ni * 16 + cn;
                size_t idx = ((size_t)b * 512 + m) * 4096 + n;
                out[idx] = acc[mi][ni][r] + pbv[b * 512 + m] + h2f(Xh[idx]);
            }
}

// ---------------------------------------------------------------------------
// ws layout (bytes), high-water ~118 MiB:
//   Wq2  [512][1024] f16   @ 0          (1048576)
//   Wkh  [512][512]  f16   @ 1048576    (524288)
//   WvT  [512][512]  f16   @ 1572864    (524288)
//   s    [8][512]    f32   @ 2097152    (16384)
//   ubar [8][512]    f32   @ 2113536    (16384)
//   vv   [8][512]    f32   @ 2129920    (16384)
//   pbv  [8][512]    f32   @ 2146304    (16384)
//   Xh   [8][512][4096] f16 @ 2162688   (33554432)
//   XT   [8][4096][512] f16 @ 35717120  (33554432)
//   Gp   [4][8][512][512] f32 @ 69271552 (33554432)
//   Ghl  [8][512][1024] f16 @ 102825984 (8388608)
//   Tb   [8][512][512] f16  @ 111214592 (4194304)
//   P    [8][512][512] f16  @ 115408896 (4194304)
//   M2   [8][512][512] f16  @ 119603200 (4194304)
// ---------------------------------------------------------------------------
extern "C" void kernel_launch(void* const* d_in, const int* in_sizes, int n_in,
                              void* d_out, int out_size, void* d_ws, size_t ws_size,
                              hipStream_t stream)
{
    const float* x  = (const float*)d_in[0];
    const float* wq = (const float*)d_in[1];
    const float* bq = (const float*)d_in[2];
    const float* wk = (const float*)d_in[3];
    const float* bk = (const float*)d_in[4];
    const float* wv = (const float*)d_in[5];
    const float* bv = (const float*)d_in[6];
    float* out = (float*)d_out;

    char* ws = (char*)d_ws;
    u16*   Wq2  = (u16*)(ws);
    u16*   Wkh  = (u16*)(ws + 1048576);
    u16*   WvT  = (u16*)(ws + 1572864);
    float* s    = (float*)(ws + 2097152);
    float* ubar = (float*)(ws + 2113536);
    float* vv   = (float*)(ws + 2129920);
    float* pbv  = (float*)(ws + 2146304);
    u16*   Xh   = (u16*)(ws + 2162688);
    u16*   XT   = (u16*)(ws + 35717120);
    float* Gp   = (float*)(ws + 69271552);
    u16*   Ghl  = (u16*)(ws + 102825984);
    u16*   Tb   = (u16*)(ws + 111214592);
    u16*   P    = (u16*)(ws + 115408896);
    u16*   M2   = (u16*)(ws + 119603200);

    hipMemsetAsync(s, 0, 4096 * sizeof(float), stream);
    k_convx<<<dim3(64, 8, 8), dim3(256), 0, stream>>>(x, Xh, XT, s);
    k_gram<<<dim3(896), dim3(256), 0, stream>>>(Xh, Gp, wq, wk, wv, Wq2, Wkh, WvT);
    k_gred<<<dim3(2048), dim3(256), 0, stream>>>(Gp, Ghl, wq, bq, wk, s, ubar, vv);
    k_T<<<dim3(4, 4, 8), dim3(256), 0, stream>>>(Wq2, Ghl, Tb);
    k_S<<<dim3(32, 8), dim3(512), 0, stream>>>(Tb, Wkh, ubar, vv, bq, bk, bv, P, pbv);
    k_M<<<dim3(4, 4, 8), dim3(256), 0, stream>>>(P, WvT, M2);
    k_out<<<dim3(1024), dim3(256), 0, stream>>>(M2, XT, Xh, pbv, out);
}

// Round 8
// 246.829 us; speedup vs baseline: 1.0737x; 1.0034x over previous
//
#include <hip/hip_runtime.h>
#include <cstdint>

typedef unsigned short u16;
typedef unsigned int   u32;
typedef _Float16 f16;

typedef __attribute__((ext_vector_type(8))) _Float16 f16x8;   // 8 fp16 = 4 VGPRs
typedef __attribute__((ext_vector_type(4))) float    f32x4;   // MFMA accumulator

__device__ __forceinline__ u16 f2h(float f) {
    union { f16 h; u16 u; } c; c.h = (f16)f; return c.u;      // v_cvt_f16_f32 RTNE
}
__device__ __forceinline__ float h2f(u16 u) {
    union { u16 u; f16 h; } c; c.u = u; return (float)c.h;
}

// async global->LDS, 16B per lane; LDS dest = wave-uniform base + lane*16
__device__ __forceinline__ void async_copy16(const u16* g, u16* lds) {
    __builtin_amdgcn_global_load_lds(
        (const __attribute__((address_space(1))) void*)g,
        (__attribute__((address_space(3))) void*)lds,
        16, 0, 0);
}

// ---------------------------------------------------------------------------
// fp16 NT GEMM core, BK=64 as two 32-wide sub-tiles (proven r3 structure):
//   C[128,128] += A[128,K] * B[128,K]^T, K contiguous both.
// 256 thr = 4 waves (2x2), each wave 64x64 = 4x4 MFMA 16x16x32.
// LDS 32 KB: As0@0, As1@4096, Bs0@8192, Bs1@12288 (u16), each [128][32]
// XOR-swizzled (0 bank conflicts measured).  stage -> sync -> 2x compute -> sync.
// ---------------------------------------------------------------------------
__device__ __forceinline__ void gemm_nt_f16(
    u16* smem, const u16* __restrict__ A, int lda,
    const u16* __restrict__ B, int ldb, int K, f32x4 acc[4][4])
{
    const int t = threadIdx.x, w = t >> 6, lane = t & 63;
    const int srow = lane >> 2;                    // 0..15 within chunk
    const int skc  = (((lane & 3) ^ ((lane >> 3) & 3)) * 8);  // swizzled
    const int ra0 = (w*2+0)*16 + srow, ra1 = (w*2+1)*16 + srow;
    const u16* gA0 = A + (size_t)ra0 * lda + skc;
    const u16* gA1 = A + (size_t)ra1 * lda + skc;
    const u16* gB0 = B + (size_t)ra0 * ldb + skc;
    const u16* gB1 = B + (size_t)ra1 * ldb + skc;
    u16* lA0 = smem + (w*2+0)*512;                 // row base within a 32-wide tile
    u16* lA1 = smem + (w*2+1)*512;
    const int fr = lane & 15, fq = lane >> 4;
    const int fc = (fq ^ ((fr >> 1) & 3)) * 8;     // swizzled fragment chunk
    const int wm = (w >> 1) * 64, wn = (w & 1) * 64;
    const int fAo = (wm + fr) * 32 + fc;
    const int fBo = (wn + fr) * 32 + fc;

    for (int k0 = 0; k0 < K; k0 += 64) {
        async_copy16(gA0 + k0,      lA0);
        async_copy16(gA1 + k0,      lA1);
        async_copy16(gA0 + k0 + 32, lA0 + 4096);
        async_copy16(gA1 + k0 + 32, lA1 + 4096);
        async_copy16(gB0 + k0,      lA0 + 8192);
        async_copy16(gB1 + k0,      lA1 + 8192);
        async_copy16(gB0 + k0 + 32, lA0 + 12288);
        async_copy16(gB1 + k0 + 32, lA1 + 12288);
        __syncthreads();
        {   // k-sub 0
            f16x8 af[4], bf[4];
#pragma unroll
            for (int i = 0; i < 4; i++) af[i] = *(const f16x8*)(smem + fAo + i * 512);
#pragma unroll
            for (int i = 0; i < 4; i++) bf[i] = *(const f16x8*)(smem + 8192 + fBo + i * 512);
#pragma unroll
            for (int mi = 0; mi < 4; mi++)
#pragma unroll
                for (int ni = 0; ni < 4; ni++)
                    acc[mi][ni] = __builtin_amdgcn_mfma_f32_16x16x32_f16(
                        af[mi], bf[ni], acc[mi][ni], 0, 0, 0);
        }
        {   // k-sub 1
            f16x8 af[4], bf[4];
#pragma unroll
            for (int i = 0; i < 4; i++) af[i] = *(const f16x8*)(smem + 4096 + fAo + i * 512);
#pragma unroll
            for (int i = 0; i < 4; i++) bf[i] = *(const f16x8*)(smem + 12288 + fBo + i * 512);
#pragma unroll
            for (int mi = 0; mi < 4; mi++)
#pragma unroll
                for (int ni = 0; ni < 4; ni++)
                    acc[mi][ni] = __builtin_amdgcn_mfma_f32_16x16x32_f16(
                        af[mi], bf[ni], acc[mi][ni], 0, 0, 0);
        }
        __syncthreads();
    }
}

__device__ __forceinline__ void zero_acc(f32x4 acc[4][4]) {
#pragma unroll
    for (int i = 0; i < 4; i++)
#pragma unroll
        for (int j = 0; j < 4; j++) {
            f32x4 z = {0.f, 0.f, 0.f, 0.f};
            acc[i][j] = z;
        }
}

// ---------------------------------------------------------------------------
// k_convx: blocks 0..4095:  x f32 [B,512,4096] -> Xh f16 + XT f16 [B,4096,512]
//                           + rowsums s (f32 atomics, s zeroed via memset)
//          blocks 4096..4607: prep Wq -> [Wq|Wq] f16, Wk -> f16
//          blocks 4608..4671: prep WvT[c][d] = f16(wv[d][c])
// (prep is independent of x; rides in convx's latency slack instead of its
//  own serial launch.  W buffers consumed later by k_T/k_S/k_M.)
// ---------------------------------------------------------------------------
__global__ __launch_bounds__(256) void k_convx(const float* __restrict__ x,
                                               u16* __restrict__ Xh,
                                               u16* __restrict__ XT,
                                               float* __restrict__ s,
                                               const float* __restrict__ wq,
                                               const float* __restrict__ wk,
                                               const float* __restrict__ wv,
                                               u16* __restrict__ Wq2,
                                               u16* __restrict__ Wkh,
                                               u16* __restrict__ WvT)
{
    __shared__ u16 tile[64][70];
    const int bid = blockIdx.x;
    const int t  = threadIdx.x;
    if (bid < 4096) {
        const int n0 = (bid & 63) * 64;
        const int c0 = ((bid >> 6) & 7) * 64;
        const int b  = bid >> 9;
        const int rr   = t >> 4;
        const int col4 = (t & 15) * 4;

        const float* src = x + ((size_t)b * 512 + c0) * 4096 + n0;
        u16* xh = Xh + ((size_t)b * 512 + c0) * 4096 + n0;
#pragma unroll
        for (int i = 0; i < 4; i++) {
            int row = i * 16 + rr;
            float4 v = *(const float4*)(src + (size_t)row * 4096 + col4);
            ushort4 h;
            h.x = f2h(v.x); h.y = f2h(v.y); h.z = f2h(v.z); h.w = f2h(v.w);
            *(ushort4*)&tile[row][col4] = h;
            *(ushort4*)(xh + (size_t)row * 4096 + col4) = h;
            float p = v.x + v.y + v.z + v.w;
            p += __shfl_xor(p, 1); p += __shfl_xor(p, 2);
            p += __shfl_xor(p, 4); p += __shfl_xor(p, 8);
            if ((t & 15) == 0) atomicAdd(&s[b * 512 + c0 + row], p);
        }
        __syncthreads();
        u16* dst = XT + ((size_t)b * 4096 + n0) * 512 + c0;
#pragma unroll
        for (int i = 0; i < 4; i++) {
            int nrow = i * 16 + rr;
            ushort4 o;
            o.x = tile[col4 + 0][nrow];
            o.y = tile[col4 + 1][nrow];
            o.z = tile[col4 + 2][nrow];
            o.w = tile[col4 + 3][nrow];
            *(ushort4*)(dst + (size_t)nrow * 512 + col4) = o;
        }
    } else if (bid < 4608) {
        const int tt = (bid - 4096) * 256 + t;          // 0..131071
        const int e = tt * 4;
        const int sel = e >> 18;                        // 0: wq, 1: wk
        const int off = e & 262143;
        const float* src = sel ? wk : wq;
        float4 v = *(const float4*)(src + off);
        ushort4 h;
        h.x = f2h(v.x); h.y = f2h(v.y); h.z = f2h(v.z); h.w = f2h(v.w);
        if (sel == 0) {
            int i = off >> 9, c = off & 511;
            *(ushort4*)(Wq2 + (size_t)i * 1024 + c) = h;
            *(ushort4*)(Wq2 + (size_t)i * 1024 + 512 + c) = h;
        } else {
            *(ushort4*)(Wkh + off) = h;
        }
    } else {
        const int bx = bid - 4608;                      // 0..63
        const int d0 = (bx >> 3) * 64;
        const int c0 = (bx & 7) * 64;
        const int rr = t >> 4, col4 = (t & 15) * 4;
#pragma unroll
        for (int i = 0; i < 4; i++) {
            int row = i * 16 + rr;                      // d offset
            float4 v = *(const float4*)(wv + (size_t)(d0 + row) * 512 + c0 + col4);
            ushort4 h;
            h.x = f2h(v.x); h.y = f2h(v.y); h.z = f2h(v.z); h.w = f2h(v.w);
            *(ushort4*)&tile[row][col4] = h;
        }
        __syncthreads();
#pragma unroll
        for (int i = 0; i < 4; i++) {
            int crow = i * 16 + rr;                     // c offset
            ushort4 o;
            o.x = tile[col4 + 0][crow];
            o.y = tile[col4 + 1][crow];
            o.z = tile[col4 + 2][crow];
            o.w = tile[col4 + 3][crow];
            *(ushort4*)(WvT + (size_t)(c0 + crow) * 512 + d0 + col4) = o;
        }
    }
}

// ---------------------------------------------------------------------------
// k_gram: symmetric Gram, XCD-swizzled.  Only the 10 upper-triangle 128^2
// tiles computed; off-diagonal tiles mirror-write the transposed tile.
// Gp[ks][b] = Xh[b, :, ks*1024:+1024] * (same)^T   split-K=4, f32 out.
// grid (320): each XCD gets a contiguous 40-block chunk (~one batch's Xh).
// ---------------------------------------------------------------------------
__global__ __launch_bounds__(256, 4) void k_gram(const u16* __restrict__ Xh,
                                                 float* __restrict__ Gp)
{
    __shared__ u16 smem[16384];          // 32 KB
    const int flat = blockIdx.x;         // 0..319
    const int swz  = (flat & 7) * 40 + (flat >> 3);   // bijective (320%8==0)
    const int tI = swz % 10;             // 0..9 upper-triangle tile
    const int bz = swz / 10;             // b*4 + ks
    const int tm = (tI >= 9) ? 3 : (tI >= 7) ? 2 : (tI >= 4) ? 1 : 0;
    const int rs = (tm == 0) ? 0 : (tm == 1) ? 4 : (tm == 2) ? 7 : 9;
    const int tn = tI - rs + tm;
    const int m0 = tm * 128, n0 = tn * 128;
    const int b  = bz >> 2, ks = bz & 3;

    const u16* Ap = Xh + (size_t)b * 512 * 4096 + (size_t)m0 * 4096 + ks * 1024;
    const u16* Bp = Xh + (size_t)b * 512 * 4096 + (size_t)n0 * 4096 + ks * 1024;

    f32x4 acc[4][4];
    zero_acc(acc);
    gemm_nt_f16(smem, Ap, 4096, Bp, 4096, 1024, acc);

    const int t = threadIdx.x, w = t >> 6, lane = t & 63;
    const int wm = (w >> 1) * 64, wn = (w & 1) * 64;
    const int cn = lane & 15, cq = lane >> 4;

    float* base = Gp + (size_t)(ks * 8 + b) * 512 * 512;
    float* outp = base + (size_t)m0 * 512 + n0;
#pragma unroll
    for (int mi = 0; mi < 4; mi++)
#pragma unroll
        for (int ni = 0; ni < 4; ni++)
#pragma unroll
            for (int r = 0; r < 4; r++) {
                int m = wm + mi * 16 + cq * 4 + r;
                int n = wn + ni * 16 + cn;
                outp[(size_t)m * 512 + n] = acc[mi][ni][r];
            }
    if (m0 != n0) {                      // mirror: G[n][m] = G[m][n]
        float* outT = base + (size_t)n0 * 512 + m0;
#pragma unroll
        for (int mi = 0; mi < 4; mi++)
#pragma unroll
            for (int ni = 0; ni < 4; ni++) {
                int mb = wm + mi * 16 + cq * 4;        // 4 consecutive m
                int n  = wn + ni * 16 + cn;
                float4 v4 = { acc[mi][ni][0], acc[mi][ni][1],
                              acc[mi][ni][2], acc[mi][ni][3] };
                *(float4*)(outT + (size_t)n * 512 + mb) = v4;
            }
    }
}

// ---------------------------------------------------------------------------
// k_gred: G = sum of 4 split-K partials; store hi/lo f16 pair
// Ghl[b][d][0:512] = hi(G[d][:]), [512:1024] = lo.
// blocks 0..127 additionally compute (fused k_uv):
//   ubar[b][i] = (Wq s_b)[i] + 4096*bq[i];  vv[b][j] = (Wk s_b)[j]
// ---------------------------------------------------------------------------
__global__ __launch_bounds__(256) void k_gred(const float* __restrict__ Gp,
                                              u16* __restrict__ Ghl,
                                              const float* __restrict__ wq,
                                              const float* __restrict__ bq,
                                              const float* __restrict__ wk,
                                              const float* __restrict__ s,
                                              float* __restrict__ ubar,
                                              float* __restrict__ vv)
{
    const size_t idx = ((size_t)blockIdx.x * 256 + threadIdx.x) * 4;
    const size_t st = (size_t)8 * 512 * 512;
    float4 g0 = *(const float4*)(Gp + idx);
    float4 g1 = *(const float4*)(Gp + idx + st);
    float4 g2 = *(const float4*)(Gp + idx + 2 * st);
    float4 g3 = *(const float4*)(Gp + idx + 3 * st);
    float gx = g0.x + g1.x + g2.x + g3.x;
    float gy = g0.y + g1.y + g2.y + g3.y;
    float gz = g0.z + g1.z + g2.z + g3.z;
    float gw = g0.w + g1.w + g2.w + g3.w;
    ushort4 hi, lo;
    hi.x = f2h(gx); lo.x = f2h(gx - h2f(hi.x));
    hi.y = f2h(gy); lo.y = f2h(gy - h2f(hi.y));
    hi.z = f2h(gz); lo.z = f2h(gz - h2f(hi.z));
    hi.w = f2h(gw); lo.w = f2h(gw - h2f(hi.w));
    const size_t row = idx >> 9;                 // b*512 + d
    const int c = (int)(idx & 511);
    *(ushort4*)(Ghl + row * 1024 + c) = hi;
    *(ushort4*)(Ghl + row * 1024 + 512 + c) = lo;

    if (blockIdx.x < 128) {                      // fused k_uv
        const int b = blockIdx.x >> 4;
        const int sub = blockIdx.x & 15;
        const int which = sub >> 3;
        const int r0 = (sub & 7) * 64;
        const int t = threadIdx.x;
        const int i = r0 + (t >> 2), l4 = t & 3;
        const float* W = which ? wk : wq;
        const float* sb = s + b * 512;
        float acc = 0.f;
#pragma unroll 4
        for (int k = 0; k < 32; k++) {
            int c2 = k * 16 + l4 * 4;
            float4 w4 = *(const float4*)(W + (size_t)i * 512 + c2);
            float4 s4 = *(const float4*)(sb + c2);
            acc += w4.x * s4.x + w4.y * s4.y + w4.z * s4.z + w4.w * s4.w;
        }
        acc += __shfl_xor(acc, 1);
        acc += __shfl_xor(acc, 2);
        if (l4 == 0) {
            if (which) vv[b * 512 + i] = acc;
            else       ubar[b * 512 + i] = acc + 4096.0f * bq[i];
        }
    }
}

// ---------------------------------------------------------------------------
// k_T: T[b] = [Wq|Wq] * Ghl[b]^T  (K=1024 hi/lo => f32-precise Wq*G), f16 out
// grid (4,4,8)
// ---------------------------------------------------------------------------
__global__ __launch_bounds__(256, 4) void k_T(const u16* __restrict__ Wq2,
                                              const u16* __restrict__ Ghl,
                                              u16* __restrict__ Tb)
{
    __shared__ u16 smem[16384];
    const int n0 = blockIdx.x * 128;
    const int m0 = blockIdx.y * 128;
    const int b  = blockIdx.z;

    const u16* Ap = Wq2 + (size_t)m0 * 1024;
    const u16* Bp = Ghl + (size_t)b * 512 * 1024 + (size_t)n0 * 1024;

    f32x4 acc[4][4];
    zero_acc(acc);
    gemm_nt_f16(smem, Ap, 1024, Bp, 1024, 1024, acc);

    const int t = threadIdx.x, w = t >> 6, lane = t & 63;
    const int wm = (w >> 1) * 64, wn = (w & 1) * 64;
    const int cn = lane & 15, cq = lane >> 4;

    u16* outp = Tb + ((size_t)b * 512 + m0) * 512 + n0;
#pragma unroll
    for (int mi = 0; mi < 4; mi++)
#pragma unroll
        for (int ni = 0; ni < 4; ni++)
#pragma unroll
            for (int r = 0; r < 4; r++) {
                int m = wm + mi * 16 + cq * 4 + r;
                int n = wn + ni * 16 + cn;
                outp[(size_t)m * 512 + n] = f2h(acc[mi][ni][r]);
            }
}

// ---------------------------------------------------------------------------
// k_S: fused  S = T*Wk^T + ubar*bk^T + bq*vv^T  -> row softmax -> P (f16)
//      also pbv[b][i] = sum_j P[i][j]*bv[j]
// Block = 16 rows x full 512 cols, 1024 threads = 16 waves; wave w owns cols
// [w*32, w*32+32).  BK=32, single-buffered.
// LDS: As[512] (1KB) + Bs[512*32] (32KB) + red (3KB) ~ 36KB.  grid (32, 8).
// ---------------------------------------------------------------------------
__global__ __launch_bounds__(1024) void k_S(
    const u16* __restrict__ Tb, const u16* __restrict__ Wkh,
    const float* __restrict__ ubar, const float* __restrict__ vv,
    const float* __restrict__ bq, const float* __restrict__ bk,
    const float* __restrict__ bv,
    u16* __restrict__ P, float* __restrict__ pbv)
{
    __shared__ u16 As[512];
    __shared__ u16 Bs[16384];
    __shared__ float redm[16][16];
    __shared__ float reds[16][16][2];

    const int m0 = blockIdx.x * 16;
    const int b  = blockIdx.y;
    const int t = threadIdx.x, w = t >> 6, lane = t & 63;
    const int srow = lane >> 2;
    const int schunk = ((lane & 3) ^ ((srow >> 1) & 3)) * 8;
    const u16* gA = Tb + ((size_t)b * 512 + m0 + srow) * 512 + schunk;
    const int fr = lane & 15, fq = lane >> 4;
    const int fc = (fq ^ ((fr >> 1) & 3)) * 8;

    f32x4 acc[2];
#pragma unroll
    for (int i = 0; i < 2; i++) { f32x4 z = {0.f,0.f,0.f,0.f}; acc[i] = z; }

    for (int k0 = 0; k0 < 512; k0 += 32) {
        if (w == 0) async_copy16(gA + k0, As);
#pragma unroll
        for (int ii = 0; ii < 2; ii++) {
            int rbase = w * 32 + ii * 16;
            async_copy16(Wkh + (size_t)(rbase + srow) * 512 + k0 + schunk,
                         Bs + rbase * 32);
        }
        __syncthreads();
        f16x8 af = *(const f16x8*)(As + fr * 32 + fc);
#pragma unroll
        for (int ni = 0; ni < 2; ni++) {
            f16x8 bf = *(const f16x8*)(Bs + (w * 32 + ni * 16 + fr) * 32 + fc);
            acc[ni] = __builtin_amdgcn_mfma_f32_16x16x32_f16(af, bf, acc[ni], 0, 0, 0);
        }
        __syncthreads();
    }

    const int cn = lane & 15, cq = lane >> 4;
    float ub[4], bqr[4];
#pragma unroll
    for (int r = 0; r < 4; r++) {
        int i = m0 + cq * 4 + r;
        ub[r]  = ubar[b * 512 + i];
        bqr[r] = bq[i];
    }
    float vj[2], bkj[2], bvj[2];
#pragma unroll
    for (int ni = 0; ni < 2; ni++) {
        int j = w * 32 + ni * 16 + cn;
        vj[ni]  = vv[b * 512 + j];
        bkj[ni] = bk[j];
        bvj[ni] = bv[j];
    }
    float sv[2][4], mr[4];
#pragma unroll
    for (int r = 0; r < 4; r++) mr[r] = -1e30f;
#pragma unroll
    for (int ni = 0; ni < 2; ni++)
#pragma unroll
        for (int r = 0; r < 4; r++) {
            sv[ni][r] = acc[ni][r] + ub[r] * bkj[ni] + bqr[r] * vj[ni];
            mr[r] = fmaxf(mr[r], sv[ni][r]);
        }
#pragma unroll
    for (int r = 0; r < 4; r++)
        for (int o = 1; o < 16; o <<= 1) mr[r] = fmaxf(mr[r], __shfl_xor(mr[r], o));
    if (cn == 0) {
#pragma unroll
        for (int r = 0; r < 4; r++) redm[cq * 4 + r][w] = mr[r];
    }
    __syncthreads();
#pragma unroll
    for (int r = 0; r < 4; r++) {
        int row = cq * 4 + r;
        float m = redm[row][0];
#pragma unroll
        for (int ww = 1; ww < 16; ww++) m = fmaxf(m, redm[row][ww]);
        mr[r] = m;
    }
    float e[2][4], se[4], sebv[4];
#pragma unroll
    for (int r = 0; r < 4; r++) { se[r] = 0.f; sebv[r] = 0.f; }
#pragma unroll
    for (int ni = 0; ni < 2; ni++)
#pragma unroll
        for (int r = 0; r < 4; r++) {
            float ev = __expf(sv[ni][r] - mr[r]);
            e[ni][r] = ev;
            se[r]   += ev;
            sebv[r] += ev * bvj[ni];
        }
#pragma unroll
    for (int r = 0; r < 4; r++)
        for (int o = 1; o < 16; o <<= 1) {
            se[r]   += __shfl_xor(se[r], o);
            sebv[r] += __shfl_xor(sebv[r], o);
        }
    if (cn == 0) {
#pragma unroll
        for (int r = 0; r < 4; r++) {
            reds[cq * 4 + r][w][0] = se[r];
            reds[cq * 4 + r][w][1] = sebv[r];
        }
    }
    __syncthreads();
#pragma unroll
    for (int r = 0; r < 4; r++) {
        int row = cq * 4 + r;
        float S = 0.f, SB = 0.f;
#pragma unroll
        for (int ww = 0; ww < 16; ww++) {
            S  += reds[row][ww][0];
            SB += reds[row][ww][1];
        }
        float inv = 1.0f / S;
#pragma unroll
        for (int ni = 0; ni < 2; ni++)
            P[((size_t)b * 512 + m0 + row) * 512 + w * 32 + ni * 16 + cn] =
                f2h(e[ni][r] * inv);
        if (w == 0 && cn == 0) pbv[b * 512 + m0 + row] = SB * inv;
    }
}

// ---------------------------------------------------------------------------
// k_M: M2[b] = P[b] * Wv  (contraction over P cols / Wv rows => B = WvT), f16
// grid (4,4,8)
// ---------------------------------------------------------------------------
__global__ __launch_bounds__(256, 4) void k_M(const u16* __restrict__ P,
                                              const u16* __restrict__ WvT,
                                              u16* __restrict__ M2)
{
    __shared__ u16 smem[16384];
    const int n0 = blockIdx.x * 128;
    const int m0 = blockIdx.y * 128;
    const int b  = blockIdx.z;

    const u16* Ap = P + (size_t)b * 512 * 512 + (size_t)m0 * 512;
    const u16* Bp = WvT + (size_t)n0 * 512;

    f32x4 acc[4][4];
    zero_acc(acc);
    gemm_nt_f16(smem, Ap, 512, Bp, 512, 512, acc);

    const int t = threadIdx.x, w = t >> 6, lane = t & 63;
    const int wm = (w >> 1) * 64, wn = (w & 1) * 64;
    const int cn = lane & 15, cq = lane >> 4;

    u16* outp = M2 + ((size_t)b * 512 + m0) * 512 + n0;
#pragma unroll
    for (int mi = 0; mi < 4; mi++)
#pragma unroll
        for (int ni = 0; ni < 4; ni++)
#pragma unroll
            for (int r = 0; r < 4; r++) {
                int m = wm + mi * 16 + cq * 4 + r;
                int n = wn + ni * 16 + cn;
                outp[(size_t)m * 512 + n] = f2h(acc[mi][ni][r]);
            }
}

// ---------------------------------------------------------------------------
// k_out: out = M2 * X + pbv*1^T + x_res   (residual from Xh f16), f32 out
// grid (1024) XCD-swizzled: each XCD owns one batch (XT slice 4MB = L2).
// ---------------------------------------------------------------------------
__global__ __launch_bounds__(256, 4) void k_out(const u16* __restrict__ M2,
                                                const u16* __restrict__ XT,
                                                const u16* __restrict__ Xh,
                                                const float* __restrict__ pbv,
                                                float* __restrict__ out)
{
    __shared__ u16 smem[16384];
    const int flat = blockIdx.x;                  // 0..1023
    const int swz  = (flat & 7) * 128 + (flat >> 3);   // bijective (1024%8==0)
    const int n0 = (swz & 31) * 128;
    const int m0 = ((swz >> 5) & 3) * 128;
    const int b  = swz >> 7;

    const u16* Ap = M2 + (size_t)b * 512 * 512 + (size_t)m0 * 512;
    const u16* Bp = XT + (size_t)b * 4096 * 512 + (size_t)n0 * 512;

    f32x4 acc[4][4];
    zero_acc(acc);
    gemm_nt_f16(smem, Ap, 512, Bp, 512, 512, acc);

    const int t = threadIdx.x, w = t >> 6, lane = t & 63;
    const int wm = (w >> 1) * 64, wn = (w & 1) * 64;
    const int cn = lane & 15, cq = lane >> 4;

#pragma unroll
    for (int mi = 0; mi < 4; mi++)
#pragma unroll
        for (int ni = 0; ni < 4; ni++)
#pragma unroll
            for (int r = 0; r < 4; r++) {
                int m = m0 + wm + mi * 16 + cq * 4 + r;
                int n = n0 + wn + ni * 16 + cn;
                size_t idx = ((size_t)b * 512 + m) * 4096 + n;
                out[idx] = acc[mi][ni][r] + pbv[b * 512 + m] + h2f(Xh[idx]);
            }
}

// ---------------------------------------------------------------------------
// ws layout (bytes), high-water ~118 MiB:
//   Wq2  [512][1024] f16   @ 0          (1048576)
//   Wkh  [512][512]  f16   @ 1048576    (524288)
//   WvT  [512][512]  f16   @ 1572864    (524288)
//   s    [8][512]    f32   @ 2097152    (16384)
//   ubar [8][512]    f32   @ 2113536    (16384)
//   vv   [8][512]    f32   @ 2129920    (16384)
//   pbv  [8][512]    f32   @ 2146304    (16384)
//   Xh   [8][512][4096] f16 @ 2162688   (33554432)
//   XT   [8][4096][512] f16 @ 35717120  (33554432)
//   Gp   [4][8][512][512] f32 @ 69271552 (33554432)
//   Ghl  [8][512][1024] f16 @ 102825984 (8388608)
//   Tb   [8][512][512] f16  @ 111214592 (4194304)
//   P    [8][512][512] f16  @ 115408896 (4194304)
//   M2   [8][512][512] f16  @ 119603200 (4194304)
// ---------------------------------------------------------------------------
extern "C" void kernel_launch(void* const* d_in, const int* in_sizes, int n_in,
                              void* d_out, int out_size, void* d_ws, size_t ws_size,
                              hipStream_t stream)
{
    const float* x  = (const float*)d_in[0];
    const float* wq = (const float*)d_in[1];
    const float* bq = (const float*)d_in[2];
    const float* wk = (const float*)d_in[3];
    const float* bk = (const float*)d_in[4];
    const float* wv = (const float*)d_in[5];
    const float* bv = (const float*)d_in[6];
    float* out = (float*)d_out;

    char* ws = (char*)d_ws;
    u16*   Wq2  = (u16*)(ws);
    u16*   Wkh  = (u16*)(ws + 1048576);
    u16*   WvT  = (u16*)(ws + 1572864);
    float* s    = (float*)(ws + 2097152);
    float* ubar = (float*)(ws + 2113536);
    float* vv   = (float*)(ws + 2129920);
    float* pbv  = (float*)(ws + 2146304);
    u16*   Xh   = (u16*)(ws + 2162688);
    u16*   XT   = (u16*)(ws + 35717120);
    float* Gp   = (float*)(ws + 69271552);
    u16*   Ghl  = (u16*)(ws + 102825984);
    u16*   Tb   = (u16*)(ws + 111214592);
    u16*   P    = (u16*)(ws + 115408896);
    u16*   M2   = (u16*)(ws + 119603200);

    hipMemsetAsync(s, 0, 4096 * sizeof(float), stream);
    k_convx<<<dim3(4672), dim3(256), 0, stream>>>(x, Xh, XT, s,
                                                  wq, wk, wv, Wq2, Wkh, WvT);
    k_gram<<<dim3(320), dim3(256), 0, stream>>>(Xh, Gp);
    k_gred<<<dim3(2048), dim3(256), 0, stream>>>(Gp, Ghl, wq, bq, wk, s, ubar, vv);
    k_T<<<dim3(4, 4, 8), dim3(256), 0, stream>>>(Wq2, Ghl, Tb);
    k_S<<<dim3(32, 8), dim3(1024), 0, stream>>>(Tb, Wkh, ubar, vv, bq, bk, bv, P, pbv);
    k_M<<<dim3(4, 4, 8), dim3(256), 0, stream>>>(P, WvT, M2);
    k_out<<<dim3(1024), dim3(256), 0, stream>>>(M2, XT, Xh, pbv, out);
}